// Round 1
// baseline (1800.254 us; speedup 1.0000x reference)
//
#include <hip/hip_runtime.h>
#include <cmath>
#include <cstdint>
#include <cstddef>

// Problem constants: B=4, C=256, H=W=256, DS=4 -> h=w=64, N=4096, Cq=16
#define NB 4
#define NC 256
#define ND 4096   // tokens per batch (64*64)
#define NCQ 16

// Workspace layout (bytes)
static const size_t OFF_XD   = 0;                 // [B][C][4096] fp32, 16 MB (aliased by out_ds later)
static const size_t OFF_QT   = 16777216;          // [B][4096][16] fp32, 1 MB
static const size_t OFF_KT   = 17825792;          // [B][4096][16] fp32, 1 MB
static const size_t OFF_V    = 18874368;          // [B][4096][256] fp32, 16 MB
static const size_t OFF_SQ   = 35651584;          // 64 floats
static const size_t OFF_SK   = 35651840;          // 64 floats
static const size_t OFF_MEAN = 35652096;          // 1 float

// ---------------- maxpool 4x4 ----------------
__global__ __launch_bounds__(256) void k_maxpool(const float* __restrict__ x,
                                                 float* __restrict__ xd) {
  unsigned idx = blockIdx.x * 256u + threadIdx.x;      // < 4*256*64*64 = 4194304
  unsigned xo = idx & 63u;
  unsigned yo = (idx >> 6) & 63u;
  unsigned bc = idx >> 12;                             // b*256 + c
  const float* base = x + (size_t)bc * 65536u + yo * 1024u + xo * 4u;
  float m = -1e30f;
#pragma unroll
  for (int dy = 0; dy < 4; ++dy) {
    float4 v = *reinterpret_cast<const float4*>(base + dy * 256);
    m = fmaxf(m, fmaxf(fmaxf(v.x, v.y), fmaxf(v.z, v.w)));
  }
  xd[(size_t)bc * 4096u + yo * 64u + xo] = m;
}

// ---------------- q,k 1x1 convs (C=256 -> 16), transposed outputs [B][N][16] ----------------
__global__ __launch_bounds__(256) void k_qk(const float* __restrict__ xd,
                                            const float* __restrict__ Wq, const float* __restrict__ bq,
                                            const float* __restrict__ Wk, const float* __restrict__ bk,
                                            float* __restrict__ qT, float* __restrict__ kT) {
  int b = blockIdx.x >> 4, nt = blockIdx.x & 15;
  int n = nt * 256 + threadIdx.x;
  const float* xp = xd + (size_t)b * 1048576u + n;
  float qa[16], ka[16];
#pragma unroll
  for (int o = 0; o < 16; ++o) { qa[o] = 0.f; ka[o] = 0.f; }
  for (int c = 0; c < 256; ++c) {
    float xv = xp[(size_t)c * 4096u];
#pragma unroll
    for (int o = 0; o < 16; ++o) {
      qa[o] = fmaf(Wq[o * 256 + c], xv, qa[o]);
      ka[o] = fmaf(Wk[o * 256 + c], xv, ka[o]);
    }
  }
  float* qo = qT + ((size_t)b * 4096u + n) * 16u;
  float* ko = kT + ((size_t)b * 4096u + n) * 16u;
#pragma unroll
  for (int o = 0; o < 16; ++o) {
    qo[o] = qa[o] + bq[o];
    ko[o] = ka[o] + bk[o];
  }
}

// ---------------- v 1x1 conv (256 -> 256), output [B][N][256] ----------------
__global__ __launch_bounds__(256) void k_v(const float* __restrict__ xd,
                                           const float* __restrict__ Wv, const float* __restrict__ bv,
                                           float* __restrict__ v) {
  __shared__ float xs[256][64];
  int b = blockIdx.x >> 6, nt = blockIdx.x & 63;
  int n0 = nt * 64;
  int tid = threadIdx.x;
  {
    const float* src = xd + (size_t)b * 1048576u + n0;
#pragma unroll
    for (int i = 0; i < 16; ++i) {
      int l4 = tid + i * 256;          // 0..4095 float4 slots
      int c = l4 >> 4, q = l4 & 15;
      float4 val = *reinterpret_cast<const float4*>(src + (size_t)c * 4096u + q * 4);
      *reinterpret_cast<float4*>(&xs[c][q * 4]) = val;
    }
  }
  __syncthreads();
  int c = tid;  // output channel
  float acc[64];
#pragma unroll
  for (int j = 0; j < 64; ++j) acc[j] = 0.f;
  const float4* wrow = reinterpret_cast<const float4*>(Wv + (size_t)c * 256u);
  for (int cc4 = 0; cc4 < 64; ++cc4) {
    float4 w4 = wrow[cc4];
#pragma unroll
    for (int u = 0; u < 4; ++u) {
      float w = (u == 0) ? w4.x : (u == 1) ? w4.y : (u == 2) ? w4.z : w4.w;
      int cc = cc4 * 4 + u;
      const float4* xr = reinterpret_cast<const float4*>(&xs[cc][0]);
#pragma unroll
      for (int j4 = 0; j4 < 16; ++j4) {
        float4 xv = xr[j4];
        acc[j4 * 4 + 0] = fmaf(w, xv.x, acc[j4 * 4 + 0]);
        acc[j4 * 4 + 1] = fmaf(w, xv.y, acc[j4 * 4 + 1]);
        acc[j4 * 4 + 2] = fmaf(w, xv.z, acc[j4 * 4 + 2]);
        acc[j4 * 4 + 3] = fmaf(w, xv.w, acc[j4 * 4 + 3]);
      }
    }
  }
  float bb = bv[c];
  for (int n = 0; n < 64; ++n) {
    v[((size_t)b * 4096u + n0 + n) * 256u + c] = acc[n] + bb;
  }
}

// ---------------- per-(b,o) column sums of q,k ----------------
__global__ __launch_bounds__(64) void k_sum(const float* __restrict__ qT, const float* __restrict__ kT,
                                            float* __restrict__ Sq, float* __restrict__ Sk) {
  int b = blockIdx.x >> 4, o = blockIdx.x & 15;
  int t = threadIdx.x;
  float sq = 0.f, sk = 0.f;
  for (int n = t; n < 4096; n += 64) {
    sq += qT[((size_t)b * 4096u + n) * 16u + o];
    sk += kT[((size_t)b * 4096u + n) * 16u + o];
  }
#pragma unroll
  for (int off = 32; off > 0; off >>= 1) {
    sq += __shfl_down(sq, off);
    sk += __shfl_down(sk, off);
  }
  if (t == 0) { Sq[blockIdx.x] = sq; Sk[blockIdx.x] = sk; }
}

// ---------------- scalar mean of att ----------------
__global__ __launch_bounds__(64) void k_mean(const float* __restrict__ Sq, const float* __restrict__ Sk,
                                             float* __restrict__ meanp) {
  int t = threadIdx.x;
  float p = Sq[t] * Sk[t];
#pragma unroll
  for (int off = 32; off > 0; off >>= 1) p += __shfl_down(p, off);
  if (t == 0) *meanp = p * (1.0f / 67108864.0f);   // / (B*N*N)
}

// ---------------- flash masked-softmax * V ----------------
// grid: B * 64 row-tiles (64 rows each), 512 threads.
// thread t: row r = t&63, channel group g = t>>6 (32 channels each)
__global__ __launch_bounds__(512) void k_flash(const float* __restrict__ qT, const float* __restrict__ kT,
                                               const float* __restrict__ v, const float* __restrict__ meanp,
                                               float* __restrict__ ods) {
  __shared__ float k_s[32][17];
  __shared__ float s_s[64][33];
  __shared__ float v_s[32][256];
  int b = blockIdx.x >> 6, rt = blockIdx.x & 63;
  int row0 = rt * 64;
  int tid = threadIdx.x;
  int r = tid & 63;
  int g = tid >> 6;
  int c0 = g * 32;
  float mean = *meanp;
  float q_reg[16];
  {
    const float* qrow = qT + ((size_t)b * 4096u + row0 + r) * 16u;
#pragma unroll
    for (int i = 0; i < 16; ++i) q_reg[i] = qrow[i];
  }
  float O[32];
#pragma unroll
  for (int j = 0; j < 32; ++j) O[j] = 0.f;
  float M = -INFINITY, L = 0.f;

  for (int t = 0; t < 128; ++t) {
    int m0 = t * 32;
    // load k tile: 32x16
    {
      int m = tid >> 4, cc = tid & 15;
      k_s[m][cc] = kT[((size_t)b * 4096u + m0 + m) * 16u + cc];
    }
    // load v tile: 32x256 = 2048 float4
    {
      const float4* src = reinterpret_cast<const float4*>(v + ((size_t)b * 4096u + m0) * 256u);
      float4* dst = reinterpret_cast<float4*>(&v_s[0][0]);
#pragma unroll
      for (int i = 0; i < 4; ++i) dst[tid + i * 512] = src[tid + i * 512];
    }
    __syncthreads();
    // scores: wave g computes m = g*4 .. g*4+3 for its lane's row r
    {
#pragma unroll
      for (int jj = 0; jj < 4; ++jj) {
        int m = g * 4 + jj;
        float acc = 0.f;
#pragma unroll
        for (int cc = 0; cc < 16; ++cc) acc = fmaf(q_reg[cc], k_s[m][cc], acc);
        s_s[r][m] = (acc < mean) ? 0.f : acc;   // mask-as-zero BEFORE softmax
      }
    }
    __syncthreads();
    // online softmax over this tile (each thread redundantly tracks its row)
    float tmax = -INFINITY;
#pragma unroll
    for (int m = 0; m < 32; ++m) tmax = fmaxf(tmax, s_s[r][m]);
    float Mn = fmaxf(M, tmax);
    float scale = __expf(M - Mn);   // first tile: exp(-inf)=0
    L *= scale;
#pragma unroll
    for (int j = 0; j < 32; ++j) O[j] *= scale;
#pragma unroll 4
    for (int m = 0; m < 32; ++m) {
      float p = __expf(s_s[r][m] - Mn);
      L += p;
      const float4* vr = reinterpret_cast<const float4*>(&v_s[m][c0]);
#pragma unroll
      for (int j4 = 0; j4 < 8; ++j4) {
        float4 vv = vr[j4];
        O[j4 * 4 + 0] = fmaf(p, vv.x, O[j4 * 4 + 0]);
        O[j4 * 4 + 1] = fmaf(p, vv.y, O[j4 * 4 + 1]);
        O[j4 * 4 + 2] = fmaf(p, vv.z, O[j4 * 4 + 2]);
        O[j4 * 4 + 3] = fmaf(p, vv.w, O[j4 * 4 + 3]);
      }
    }
    M = Mn;
    __syncthreads();
  }
  float inv = 1.f / L;
  float* orow = ods + (((size_t)b * 4096u + row0 + r) * 256u + c0);
#pragma unroll
  for (int j4 = 0; j4 < 8; ++j4) {
    float4 o4 = make_float4(O[j4 * 4 + 0] * inv, O[j4 * 4 + 1] * inv,
                            O[j4 * 4 + 2] * inv, O[j4 * 4 + 3] * inv);
    *reinterpret_cast<float4*>(orow + j4 * 4) = o4;
  }
}

// ---------------- bilinear 4x upsample (half-pixel, edge clamp) + residual ----------------
__global__ __launch_bounds__(256) void k_up(const float* __restrict__ ods, const float* __restrict__ x,
                                            float* __restrict__ out) {
  size_t idx = (size_t)blockIdx.x * 256u + threadIdx.x;   // < 4*256*256*256
  int j = (int)(idx & 255u);
  int i = (int)((idx >> 8) & 255u);
  size_t bc = idx >> 16;         // b*256 + c
  int b = (int)(bc >> 8);
  int c = (int)(bc & 255u);

  float py = (i + 0.5f) * 0.25f - 0.5f;
  float y0f = floorf(py);
  float wy = py - y0f;
  int y0 = (int)y0f, y1 = y0 + 1;
  y0 = max(y0, 0); y1 = min(y1, 63);

  float px = (j + 0.5f) * 0.25f - 0.5f;
  float x0f = floorf(px);
  float wx = px - x0f;
  int x0 = (int)x0f, x1 = x0 + 1;
  x0 = max(x0, 0); x1 = min(x1, 63);

  const float* gbase = ods + (size_t)b * 4096u * 256u + c;
  float g00 = gbase[(size_t)(y0 * 64 + x0) * 256u];
  float g01 = gbase[(size_t)(y0 * 64 + x1) * 256u];
  float g10 = gbase[(size_t)(y1 * 64 + x0) * 256u];
  float g11 = gbase[(size_t)(y1 * 64 + x1) * 256u];
  float val = (1.f - wy) * ((1.f - wx) * g00 + wx * g01) + wy * ((1.f - wx) * g10 + wx * g11);
  out[idx] = val + x[idx];
}

extern "C" void kernel_launch(void* const* d_in, const int* in_sizes, int n_in,
                              void* d_out, int out_size, void* d_ws, size_t ws_size,
                              hipStream_t stream) {
  const float* x  = (const float*)d_in[0];
  const float* Wq = (const float*)d_in[1];
  const float* bq = (const float*)d_in[2];
  const float* Wk = (const float*)d_in[3];
  const float* bk = (const float*)d_in[4];
  const float* Wv = (const float*)d_in[5];
  const float* bv = (const float*)d_in[6];
  float* out = (float*)d_out;

  char* ws = (char*)d_ws;
  float* xd   = (float*)(ws + OFF_XD);
  float* qT   = (float*)(ws + OFF_QT);
  float* kT   = (float*)(ws + OFF_KT);
  float* v    = (float*)(ws + OFF_V);
  float* Sq   = (float*)(ws + OFF_SQ);
  float* Sk   = (float*)(ws + OFF_SK);
  float* mnp  = (float*)(ws + OFF_MEAN);
  float* ods  = xd;   // out_ds [B][N][256] aliases xd (xd dead after k_v)

  k_maxpool<<<dim3(16384), dim3(256), 0, stream>>>(x, xd);
  k_qk<<<dim3(64), dim3(256), 0, stream>>>(xd, Wq, bq, Wk, bk, qT, kT);
  k_v<<<dim3(256), dim3(256), 0, stream>>>(xd, Wv, bv, v);
  k_sum<<<dim3(64), dim3(64), 0, stream>>>(qT, kT, Sq, Sk);
  k_mean<<<dim3(1), dim3(64), 0, stream>>>(Sq, Sk, mnp);
  k_flash<<<dim3(256), dim3(512), 0, stream>>>(qT, kT, v, mnp, ods);
  k_up<<<dim3(262144), dim3(256), 0, stream>>>(ods, x, out);
}

// Round 2
// 1497.942 us; speedup vs baseline: 1.2018x; 1.2018x over previous
//
#include <hip/hip_runtime.h>
#include <hip/hip_bf16.h>
#include <cmath>
#include <cstdint>
#include <cstddef>

// Problem constants: B=4, C=256, H=W=256, DS=4 -> h=w=64, N=4096, Cq=16
typedef unsigned short u16;
typedef __attribute__((ext_vector_type(8))) __bf16 bf16x8;
typedef __attribute__((ext_vector_type(4))) float f32x4;
typedef __attribute__((ext_vector_type(8))) unsigned short us8;
typedef __attribute__((ext_vector_type(4))) unsigned short us4;

// Workspace layout (bytes)
static const size_t OFF_XD   = 0;            // [B][C][4096] fp32, 16 MB (aliased by out_ds later)
static const size_t OFF_QT   = 16777216;     // [B][4096][16] fp32, 1 MB
static const size_t OFF_KT   = 17825792;     // [B][4096][16] fp32, 1 MB
static const size_t OFF_VT   = 18874368;     // [B][256][4096] bf16 (V transposed), 8 MB
static const size_t OFF_SQ   = 27262976;     // 64 floats
static const size_t OFF_SK   = 27263232;     // 64 floats
static const size_t OFF_MEAN = 27263488;     // 1 float

// ---------------- maxpool 4x4 ----------------
__global__ __launch_bounds__(256) void k_maxpool(const float* __restrict__ x,
                                                 float* __restrict__ xd) {
  unsigned idx = blockIdx.x * 256u + threadIdx.x;      // < 4*256*64*64 = 4194304
  unsigned xo = idx & 63u;
  unsigned yo = (idx >> 6) & 63u;
  unsigned bc = idx >> 12;                             // b*256 + c
  const float* base = x + (size_t)bc * 65536u + yo * 1024u + xo * 4u;
  float m = -1e30f;
#pragma unroll
  for (int dy = 0; dy < 4; ++dy) {
    float4 v = *reinterpret_cast<const float4*>(base + dy * 256);
    m = fmaxf(m, fmaxf(fmaxf(v.x, v.y), fmaxf(v.z, v.w)));
  }
  xd[(size_t)bc * 4096u + yo * 64u + xo] = m;
}

// ---------------- q,k 1x1 convs (C=256 -> 16), outputs [B][N][16] ----------------
// 256 blocks x 512 threads; block handles 64 tokens. 8-way c-split + LDS reduce.
__global__ __launch_bounds__(512) void k_qk(const float* __restrict__ xd,
                                            const float* __restrict__ Wq, const float* __restrict__ bq,
                                            const float* __restrict__ Wk, const float* __restrict__ bk,
                                            float* __restrict__ qT, float* __restrict__ kT) {
  __shared__ float smem[16896];   // union: xs[256][64] (16384 f) / part[8][64][33] (16896 f)
  float (*xs)[64] = reinterpret_cast<float(*)[64]>(smem);
  float (*part)[64][33] = reinterpret_cast<float(*)[64][33]>(smem);
  int b = blockIdx.x >> 6, n0 = (blockIdx.x & 63) * 64;
  int tid = threadIdx.x;
  {
    const float* src = xd + (size_t)b * 1048576u + n0;
#pragma unroll
    for (int i = 0; i < 8; ++i) {
      int l4 = tid + i * 512;            // 0..4095 float4 slots
      int c = l4 >> 4, qq = l4 & 15;
      float4 val = *reinterpret_cast<const float4*>(src + (size_t)c * 4096u + qq * 4);
      *reinterpret_cast<float4*>(&xs[c][qq * 4]) = val;
    }
  }
  __syncthreads();
  int nl = tid & 63, pp = tid >> 6;      // pp in 0..7 -> c range pp*32..+32 (wave-uniform)
  float qa[16], ka[16];
#pragma unroll
  for (int o = 0; o < 16; ++o) { qa[o] = 0.f; ka[o] = 0.f; }
  for (int i = 0; i < 32; ++i) {
    int c = pp * 32 + i;
    float xv = xs[c][nl];
#pragma unroll
    for (int o = 0; o < 16; ++o) {
      qa[o] = fmaf(Wq[o * 256 + c], xv, qa[o]);
      ka[o] = fmaf(Wk[o * 256 + c], xv, ka[o]);
    }
  }
  __syncthreads();   // xs reads done before aliased part writes
#pragma unroll
  for (int o = 0; o < 16; ++o) {
    part[pp][nl][o]      = qa[o];
    part[pp][nl][16 + o] = ka[o];
  }
  __syncthreads();
#pragma unroll
  for (int i = 0; i < 4; ++i) {
    int idx = tid * 4 + i;               // n = idx>>5, o = idx&31
    int n = idx >> 5, o = idx & 31;
    float s = 0.f;
#pragma unroll
    for (int p = 0; p < 8; ++p) s += part[p][n][o];
    if (o < 16) qT[((size_t)b * 4096u + n0 + n) * 16u + o]        = s + bq[o];
    else        kT[((size_t)b * 4096u + n0 + n) * 16u + (o - 16)] = s + bk[o - 16];
  }
}

// ---------------- v 1x1 conv (256 -> 256), output V^T bf16 [B][256][4096] ----------------
__global__ __launch_bounds__(256) void k_v(const float* __restrict__ xd,
                                           const float* __restrict__ Wv, const float* __restrict__ bv,
                                           u16* __restrict__ vT) {
  __shared__ float xs[256][64];
  int b = blockIdx.x >> 6, nt = blockIdx.x & 63;
  int n0 = nt * 64;
  int tid = threadIdx.x;
  {
    const float* src = xd + (size_t)b * 1048576u + n0;
#pragma unroll
    for (int i = 0; i < 16; ++i) {
      int l4 = tid + i * 256;
      int c = l4 >> 4, q = l4 & 15;
      float4 val = *reinterpret_cast<const float4*>(src + (size_t)c * 4096u + q * 4);
      *reinterpret_cast<float4*>(&xs[c][q * 4]) = val;
    }
  }
  __syncthreads();
  int c = tid;
  float acc[64];
#pragma unroll
  for (int j = 0; j < 64; ++j) acc[j] = 0.f;
  const float4* wrow = reinterpret_cast<const float4*>(Wv + (size_t)c * 256u);
  for (int cc4 = 0; cc4 < 64; ++cc4) {
    float4 w4 = wrow[cc4];
#pragma unroll
    for (int u = 0; u < 4; ++u) {
      float w = (u == 0) ? w4.x : (u == 1) ? w4.y : (u == 2) ? w4.z : w4.w;
      int cc = cc4 * 4 + u;
      const float4* xr = reinterpret_cast<const float4*>(&xs[cc][0]);
#pragma unroll
      for (int j4 = 0; j4 < 16; ++j4) {
        float4 xv = xr[j4];
        acc[j4 * 4 + 0] = fmaf(w, xv.x, acc[j4 * 4 + 0]);
        acc[j4 * 4 + 1] = fmaf(w, xv.y, acc[j4 * 4 + 1]);
        acc[j4 * 4 + 2] = fmaf(w, xv.z, acc[j4 * 4 + 2]);
        acc[j4 * 4 + 3] = fmaf(w, xv.w, acc[j4 * 4 + 3]);
      }
    }
  }
  float bb = bv[c];
  u16* dst = vT + ((size_t)b * 256u + c) * 4096u + n0;
#pragma unroll
  for (int n4 = 0; n4 < 16; ++n4) {
    us4 u;
#pragma unroll
    for (int j = 0; j < 4; ++j) {
      __hip_bfloat16 h = __float2bfloat16(acc[n4 * 4 + j] + bb);
      u[j] = __builtin_bit_cast(u16, h);
    }
    *reinterpret_cast<us4*>(dst + n4 * 4) = u;
  }
}

// ---------------- per-(b,o) column sums of q,k ----------------
__global__ __launch_bounds__(64) void k_sum(const float* __restrict__ qT, const float* __restrict__ kT,
                                            float* __restrict__ Sq, float* __restrict__ Sk) {
  int b = blockIdx.x >> 4, o = blockIdx.x & 15;
  int t = threadIdx.x;
  float sq = 0.f, sk = 0.f;
  for (int n = t; n < 4096; n += 64) {
    sq += qT[((size_t)b * 4096u + n) * 16u + o];
    sk += kT[((size_t)b * 4096u + n) * 16u + o];
  }
#pragma unroll
  for (int off = 32; off > 0; off >>= 1) {
    sq += __shfl_down(sq, off);
    sk += __shfl_down(sk, off);
  }
  if (t == 0) { Sq[blockIdx.x] = sq; Sk[blockIdx.x] = sk; }
}

__global__ __launch_bounds__(64) void k_mean(const float* __restrict__ Sq, const float* __restrict__ Sk,
                                             float* __restrict__ meanp) {
  int t = threadIdx.x;
  float p = Sq[t] * Sk[t];
#pragma unroll
  for (int off = 32; off > 0; off >>= 1) p += __shfl_down(p, off);
  if (t == 0) *meanp = p * (1.0f / 67108864.0f);   // / (B*N*N)
}

__device__ __forceinline__ float dot16(const float* __restrict__ q, const float* krow) {
  float s = 0.f;
#pragma unroll
  for (int c4 = 0; c4 < 4; ++c4) {
    float4 kk = *reinterpret_cast<const float4*>(krow + c4 * 4);
    s = fmaf(q[c4 * 4 + 0], kk.x, s);
    s = fmaf(q[c4 * 4 + 1], kk.y, s);
    s = fmaf(q[c4 * 4 + 2], kk.z, s);
    s = fmaf(q[c4 * 4 + 3], kk.w, s);
  }
  return s;
}

// ---------------- two-pass masked-softmax * V with MFMA PV ----------------
// grid: B*64 blocks (64 rows each), 512 threads = 8 waves.
// pass1: exact fp32 M,L per row. pass2: P(bf16) @ V^T(bf16) via mfma 16x16x32.
__global__ __launch_bounds__(512) void k_flash(const float* __restrict__ qT,
                                               const float* __restrict__ kT,
                                               const u16* __restrict__ vT,
                                               const float* __restrict__ meanp,
                                               float* __restrict__ ods) {
  __shared__ float k_lds[256][20];   // fp32 k rows (pad 20 -> 16B aligned, ~2-way banks)
  __shared__ u16 P_lds[64][72];      // bf16 P tile (pad 72)
  __shared__ u16 V_lds[256][72];     // bf16 V^T tile (pad 72)
  __shared__ float M_s[64], L_s[64];
  int b = blockIdx.x >> 6;
  int row0 = (blockIdx.x & 63) * 64;
  int tid = threadIdx.x;
  int r = tid >> 3, t8 = tid & 7;    // 8 threads per row
  float mean = *meanp;
  float q_reg[16];
  {
    const float* qrow = qT + ((size_t)b * 4096u + row0 + r) * 16u;
#pragma unroll
    for (int i = 0; i < 16; ++i) q_reg[i] = qrow[i];
  }
  // ---- pass 1: row max + sum (fp32 exact; all effective scores >= 0) ----
  float m = 0.f, l = 0.f;
  for (int ch = 0; ch < 16; ++ch) {
    {
      const float4* g = reinterpret_cast<const float4*>(kT + ((size_t)b * 4096u + ch * 256) * 16u);
#pragma unroll
      for (int i = 0; i < 2; ++i) {
        int f = tid + i * 512;
        int kv = f >> 2, c4 = f & 3;
        *reinterpret_cast<float4*>(&k_lds[kv][c4 * 4]) = g[f];
      }
    }
    __syncthreads();
    float s_arr[32];
    float mc = 0.f;
#pragma unroll
    for (int j = 0; j < 32; ++j) {
      float s = dot16(q_reg, &k_lds[t8 * 32 + j][0]);
      s = (s < mean) ? 0.f : s;      // mask-as-zero BEFORE softmax
      s_arr[j] = s;
      mc = fmaxf(mc, s);
    }
    float mn = fmaxf(m, mc);
    float acc = 0.f;
#pragma unroll
    for (int j = 0; j < 32; ++j) acc += __expf(s_arr[j] - mn);
    l = l * __expf(m - mn) + acc;
    m = mn;
    __syncthreads();
  }
#pragma unroll
  for (int off = 1; off < 8; off <<= 1) {   // combine 8 adjacent lanes per row
    float mo = __shfl_xor(m, off);
    float lo = __shfl_xor(l, off);
    float mn = fmaxf(m, mo);
    l = l * __expf(m - mn) + lo * __expf(mo - mn);
    m = mn;
  }
  if (t8 == 0) { M_s[r] = m; L_s[r] = l; }
  __syncthreads();
  float Mrow = M_s[r];

  // ---- pass 2: P@V via MFMA, KV tiles of 64 ----
  int w = tid >> 6, lane = tid & 63;
  int wr = (w & 1) * 32, wc = (w >> 1) * 64;   // wave owns 32 rows x 64 cols
  f32x4 accv[2][4];
#pragma unroll
  for (int a = 0; a < 2; ++a)
#pragma unroll
    for (int c = 0; c < 4; ++c) accv[a][c] = (f32x4){0.f, 0.f, 0.f, 0.f};

  for (int t = 0; t < 64; ++t) {
    int kv0 = t * 64;
    if (tid < 256) {     // stage k: 64 rows x 16 f32
      const float4* g = reinterpret_cast<const float4*>(kT + ((size_t)b * 4096u + kv0) * 16u);
      int kv = tid >> 2, c4 = tid & 3;
      *reinterpret_cast<float4*>(&k_lds[kv][c4 * 4]) = g[tid];
    }
    {                    // stage V^T: 256 rows x 64 bf16
      int row = tid >> 1, half = tid & 1;
      const us8* g = reinterpret_cast<const us8*>(vT + ((size_t)b * 256u + row) * 4096u + kv0 + half * 32);
#pragma unroll
      for (int j = 0; j < 4; ++j) {
        *reinterpret_cast<us8*>(&V_lds[row][half * 32 + j * 8]) = g[j];
      }
    }
    __syncthreads();
    {                    // scores -> P bf16 (8 consecutive kv per thread)
      us8 pv;
#pragma unroll
      for (int jj = 0; jj < 8; ++jj) {
        float s = dot16(q_reg, &k_lds[t8 * 8 + jj][0]);
        s = (s < mean) ? 0.f : s;
        float p = __expf(s - Mrow);
        __hip_bfloat16 h = __float2bfloat16(p);
        pv[jj] = __builtin_bit_cast(u16, h);
      }
      *reinterpret_cast<us8*>(&P_lds[r][t8 * 8]) = pv;
    }
    __syncthreads();
    // MFMA: A=P rows, B=V^T cols; A row=lane&15, k=(lane>>4)*8+i; same for B
#pragma unroll
    for (int kk = 0; kk < 2; ++kk) {
      int kb = kk * 32 + (lane >> 4) * 8;
      bf16x8 a0 = __builtin_bit_cast(bf16x8, *reinterpret_cast<const us8*>(&P_lds[wr + (lane & 15)][kb]));
      bf16x8 a1 = __builtin_bit_cast(bf16x8, *reinterpret_cast<const us8*>(&P_lds[wr + 16 + (lane & 15)][kb]));
#pragma unroll
      for (int ct = 0; ct < 4; ++ct) {
        bf16x8 bf = __builtin_bit_cast(bf16x8, *reinterpret_cast<const us8*>(&V_lds[wc + ct * 16 + (lane & 15)][kb]));
        accv[0][ct] = __builtin_amdgcn_mfma_f32_16x16x32_bf16(a0, bf, accv[0][ct], 0, 0, 0);
        accv[1][ct] = __builtin_amdgcn_mfma_f32_16x16x32_bf16(a1, bf, accv[1][ct], 0, 0, 0);
      }
    }
    __syncthreads();
  }
  // epilogue: C/D layout col=lane&15, row=(lane>>4)*4+reg
  int colb = lane & 15, rquad = (lane >> 4) * 4;
#pragma unroll
  for (int rt = 0; rt < 2; ++rt) {
#pragma unroll
    for (int reg = 0; reg < 4; ++reg) {
      int row_g = wr + rt * 16 + rquad + reg;
      float linv = 1.f / L_s[row_g];
      float* orow = ods + (((size_t)b * 4096u) + row0 + row_g) * 256u + wc + colb;
#pragma unroll
      for (int ct = 0; ct < 4; ++ct) {
        orow[ct * 16] = accv[rt][ct][reg] * linv;
      }
    }
  }
}

// ---------------- bilinear 4x upsample (half-pixel, edge clamp) + residual ----------------
__global__ __launch_bounds__(256) void k_up(const float* __restrict__ ods, const float* __restrict__ x,
                                            float* __restrict__ out) {
  size_t idx = (size_t)blockIdx.x * 256u + threadIdx.x;
  int j = (int)(idx & 255u);
  int i = (int)((idx >> 8) & 255u);
  size_t bc = idx >> 16;
  int b = (int)(bc >> 8);
  int c = (int)(bc & 255u);

  float py = (i + 0.5f) * 0.25f - 0.5f;
  float y0f = floorf(py);
  float wy = py - y0f;
  int y0 = (int)y0f, y1 = y0 + 1;
  y0 = max(y0, 0); y1 = min(y1, 63);

  float px = (j + 0.5f) * 0.25f - 0.5f;
  float x0f = floorf(px);
  float wx = px - x0f;
  int x0 = (int)x0f, x1 = x0 + 1;
  x0 = max(x0, 0); x1 = min(x1, 63);

  const float* gbase = ods + (size_t)b * 4096u * 256u + c;
  float g00 = gbase[(size_t)(y0 * 64 + x0) * 256u];
  float g01 = gbase[(size_t)(y0 * 64 + x1) * 256u];
  float g10 = gbase[(size_t)(y1 * 64 + x0) * 256u];
  float g11 = gbase[(size_t)(y1 * 64 + x1) * 256u];
  float val = (1.f - wy) * ((1.f - wx) * g00 + wx * g01) + wy * ((1.f - wx) * g10 + wx * g11);
  out[idx] = val + x[idx];
}

extern "C" void kernel_launch(void* const* d_in, const int* in_sizes, int n_in,
                              void* d_out, int out_size, void* d_ws, size_t ws_size,
                              hipStream_t stream) {
  const float* x  = (const float*)d_in[0];
  const float* Wq = (const float*)d_in[1];
  const float* bq = (const float*)d_in[2];
  const float* Wk = (const float*)d_in[3];
  const float* bk = (const float*)d_in[4];
  const float* Wv = (const float*)d_in[5];
  const float* bv = (const float*)d_in[6];
  float* out = (float*)d_out;

  char* ws = (char*)d_ws;
  float* xd   = (float*)(ws + OFF_XD);
  float* qT   = (float*)(ws + OFF_QT);
  float* kT   = (float*)(ws + OFF_KT);
  u16*   vT   = (u16*)(ws + OFF_VT);
  float* Sq   = (float*)(ws + OFF_SQ);
  float* Sk   = (float*)(ws + OFF_SK);
  float* mnp  = (float*)(ws + OFF_MEAN);
  float* ods  = xd;   // out_ds [B][N][256] aliases xd (xd dead after k_v/k_qk)

  k_maxpool<<<dim3(16384), dim3(256), 0, stream>>>(x, xd);
  k_qk<<<dim3(256), dim3(512), 0, stream>>>(xd, Wq, bq, Wk, bk, qT, kT);
  k_v<<<dim3(256), dim3(256), 0, stream>>>(xd, Wv, bv, vT);
  k_sum<<<dim3(64), dim3(64), 0, stream>>>(qT, kT, Sq, Sk);
  k_mean<<<dim3(1), dim3(64), 0, stream>>>(Sq, Sk, mnp);
  k_flash<<<dim3(256), dim3(512), 0, stream>>>(qT, kT, vT, mnp, ods);
  k_up<<<dim3(262144), dim3(256), 0, stream>>>(ods, x, out);
}

// Round 3
// 407.291 us; speedup vs baseline: 4.4201x; 3.6778x over previous
//
#include <hip/hip_runtime.h>
#include <hip/hip_bf16.h>
#include <cmath>
#include <cstdint>
#include <cstddef>

// Problem constants: B=4, C=256, H=W=256, DS=4 -> h=w=64, N=4096, Cq=16
typedef unsigned short u16;
typedef __attribute__((ext_vector_type(8))) __bf16 bf16x8;
typedef __attribute__((ext_vector_type(4))) float f32x4;
typedef __attribute__((ext_vector_type(8))) unsigned short us8;
typedef __attribute__((ext_vector_type(4))) unsigned short us4;

// Workspace layout (bytes)
static const size_t OFF_XD   = 0;            // [B][C][4096] fp32, 16 MB (aliased by out_ds [b][c][n])
static const size_t OFF_QT   = 16777216;     // [B][4096][16] fp32, 1 MB
static const size_t OFF_KT   = 17825792;     // [B][4096][16] fp32, 1 MB
static const size_t OFF_VT   = 18874368;     // [B][256][4096] bf16 (V transposed), 8 MB
static const size_t OFF_SQ   = 27262976;     // 64 floats
static const size_t OFF_SK   = 27263232;     // 64 floats
static const size_t OFF_MEAN = 27263488;     // 1 float

__device__ __forceinline__ void gl2lds16(const void* gsrc, void* ldst) {
  __builtin_amdgcn_global_load_lds(
      (const __attribute__((address_space(1))) unsigned int*)gsrc,
      (__attribute__((address_space(3))) unsigned int*)ldst, 16, 0, 0);
}

// ---------------- maxpool 4x4 ----------------
__global__ __launch_bounds__(256) void k_maxpool(const float* __restrict__ x,
                                                 float* __restrict__ xd) {
  unsigned idx = blockIdx.x * 256u + threadIdx.x;      // < 4*256*64*64
  unsigned xo = idx & 63u;
  unsigned yo = (idx >> 6) & 63u;
  unsigned bc = idx >> 12;                             // b*256 + c
  const float* base = x + (size_t)bc * 65536u + yo * 1024u + xo * 4u;
  float m = -1e30f;
#pragma unroll
  for (int dy = 0; dy < 4; ++dy) {
    float4 v = *reinterpret_cast<const float4*>(base + dy * 256);
    m = fmaxf(m, fmaxf(fmaxf(v.x, v.y), fmaxf(v.z, v.w)));
  }
  xd[(size_t)bc * 4096u + yo * 64u + xo] = m;
}

// ---------------- q,k 1x1 convs (C=256 -> 16), outputs [B][N][16] ----------------
__global__ __launch_bounds__(512) void k_qk(const float* __restrict__ xd,
                                            const float* __restrict__ Wq, const float* __restrict__ bq,
                                            const float* __restrict__ Wk, const float* __restrict__ bk,
                                            float* __restrict__ qT, float* __restrict__ kT) {
  __shared__ float smem[16896];   // union: xs[256][64] / part[8][64][33]
  float (*xs)[64] = reinterpret_cast<float(*)[64]>(smem);
  float (*part)[64][33] = reinterpret_cast<float(*)[64][33]>(smem);
  int b = blockIdx.x >> 6, n0 = (blockIdx.x & 63) * 64;
  int tid = threadIdx.x;
  {
    const float* src = xd + (size_t)b * 1048576u + n0;
#pragma unroll
    for (int i = 0; i < 8; ++i) {
      int l4 = tid + i * 512;
      int c = l4 >> 4, qq = l4 & 15;
      *reinterpret_cast<float4*>(&xs[c][qq * 4]) =
          *reinterpret_cast<const float4*>(src + (size_t)c * 4096u + qq * 4);
    }
  }
  __syncthreads();
  int nl = tid & 63, pp = tid >> 6;
  float qa[16], ka[16];
#pragma unroll
  for (int o = 0; o < 16; ++o) { qa[o] = 0.f; ka[o] = 0.f; }
  for (int i = 0; i < 32; ++i) {
    int c = pp * 32 + i;
    float xv = xs[c][nl];
#pragma unroll
    for (int o = 0; o < 16; ++o) {
      qa[o] = fmaf(Wq[o * 256 + c], xv, qa[o]);
      ka[o] = fmaf(Wk[o * 256 + c], xv, ka[o]);
    }
  }
  __syncthreads();
#pragma unroll
  for (int o = 0; o < 16; ++o) {
    part[pp][nl][o]      = qa[o];
    part[pp][nl][16 + o] = ka[o];
  }
  __syncthreads();
#pragma unroll
  for (int i = 0; i < 4; ++i) {
    int idx = tid * 4 + i;
    int n = idx >> 5, o = idx & 31;
    float s = 0.f;
#pragma unroll
    for (int p = 0; p < 8; ++p) s += part[p][n][o];
    if (o < 16) qT[((size_t)b * 4096u + n0 + n) * 16u + o]        = s + bq[o];
    else        kT[((size_t)b * 4096u + n0 + n) * 16u + (o - 16)] = s + bk[o - 16];
  }
}

// ---------------- v 1x1 conv (256 -> 256), output V^T bf16 [B][256][4096] ----------------
// 16c x 4n register tile per thread: LDS reads cut 16x vs per-channel version.
__global__ __launch_bounds__(256) void k_v(const float* __restrict__ xd,
                                           const float* __restrict__ Wv, const float* __restrict__ bv,
                                           u16* __restrict__ vT) {
  __shared__ float xs[256][64];
  int b = blockIdx.x >> 6, nt = blockIdx.x & 63;
  int n0 = nt * 64;
  int tid = threadIdx.x;
  {
    const float* src = xd + (size_t)b * 1048576u + n0;
#pragma unroll
    for (int i = 0; i < 16; ++i) {
      int l4 = tid + i * 256;
      int c = l4 >> 4, q = l4 & 15;
      *reinterpret_cast<float4*>(&xs[c][q * 4]) =
          *reinterpret_cast<const float4*>(src + (size_t)c * 4096u + q * 4);
    }
  }
  __syncthreads();
  int ci = tid >> 4, ni = tid & 15;   // c in [ci*16, ci*16+16), n in [ni*4, ni*4+4)
  float acc[16][4];
#pragma unroll
  for (int j = 0; j < 16; ++j) { acc[j][0]=0.f; acc[j][1]=0.f; acc[j][2]=0.f; acc[j][3]=0.f; }
  for (int cc4 = 0; cc4 < 64; ++cc4) {
    float4 xv0 = *reinterpret_cast<const float4*>(&xs[cc4*4+0][ni*4]);
    float4 xv1 = *reinterpret_cast<const float4*>(&xs[cc4*4+1][ni*4]);
    float4 xv2 = *reinterpret_cast<const float4*>(&xs[cc4*4+2][ni*4]);
    float4 xv3 = *reinterpret_cast<const float4*>(&xs[cc4*4+3][ni*4]);
#pragma unroll
    for (int j = 0; j < 16; ++j) {
      float4 wv = *reinterpret_cast<const float4*>(&Wv[(size_t)(ci*16 + j) * 256u + cc4*4]);
      acc[j][0] = fmaf(wv.x, xv0.x, fmaf(wv.y, xv1.x, fmaf(wv.z, xv2.x, fmaf(wv.w, xv3.x, acc[j][0]))));
      acc[j][1] = fmaf(wv.x, xv0.y, fmaf(wv.y, xv1.y, fmaf(wv.z, xv2.y, fmaf(wv.w, xv3.y, acc[j][1]))));
      acc[j][2] = fmaf(wv.x, xv0.z, fmaf(wv.y, xv1.z, fmaf(wv.z, xv2.z, fmaf(wv.w, xv3.z, acc[j][2]))));
      acc[j][3] = fmaf(wv.x, xv0.w, fmaf(wv.y, xv1.w, fmaf(wv.z, xv2.w, fmaf(wv.w, xv3.w, acc[j][3]))));
    }
  }
#pragma unroll
  for (int j = 0; j < 16; ++j) {
    int c = ci*16 + j;
    float bb = bv[c];
    us4 u;
#pragma unroll
    for (int nn = 0; nn < 4; ++nn)
      u[nn] = __builtin_bit_cast(u16, __float2bfloat16(acc[j][nn] + bb));
    *reinterpret_cast<us4*>(vT + ((size_t)b*256 + c) * 4096u + n0 + ni*4) = u;
  }
}

// ---------------- per-(b,o) column sums of q,k ----------------
__global__ __launch_bounds__(64) void k_sum(const float* __restrict__ qT, const float* __restrict__ kT,
                                            float* __restrict__ Sq, float* __restrict__ Sk) {
  int b = blockIdx.x >> 4, o = blockIdx.x & 15;
  int t = threadIdx.x;
  float sq = 0.f, sk = 0.f;
  for (int n = t; n < 4096; n += 64) {
    sq += qT[((size_t)b * 4096u + n) * 16u + o];
    sk += kT[((size_t)b * 4096u + n) * 16u + o];
  }
#pragma unroll
  for (int off = 32; off > 0; off >>= 1) {
    sq += __shfl_down(sq, off);
    sk += __shfl_down(sk, off);
  }
  if (t == 0) { Sq[blockIdx.x] = sq; Sk[blockIdx.x] = sk; }
}

__global__ __launch_bounds__(64) void k_mean(const float* __restrict__ Sq, const float* __restrict__ Sk,
                                             float* __restrict__ meanp) {
  int t = threadIdx.x;
  float p = Sq[t] * Sk[t];
#pragma unroll
  for (int off = 32; off > 0; off >>= 1) p += __shfl_down(p, off);
  if (t == 0) *meanp = p * (1.0f / 67108864.0f);   // / (B*N*N)
}

// ---------------- one-pass MFMA flash: split-bf16 QK^T + masked softmax + PV ----------------
// 256 blocks (b x 64 q-tiles), 256 threads = 4 waves; wave w owns q rows [16w,16w+16), all 256 c.
__global__ __launch_bounds__(256) void k_flash(const float* __restrict__ qT,
                                               const float* __restrict__ kT,
                                               const u16* __restrict__ vT,
                                               const float* __restrict__ meanp,
                                               float* __restrict__ ods) {
  __shared__ u16 vbuf[2][16384];       // [buf][c row(256) x kv(64)] linear, source-swizzled
  __shared__ u16 kfh[2][4][64][8];     // B-frag [k_hi|k_hi], fragment-linear
  __shared__ u16 kfl[2][4][64][8];     // B-frag [k_lo|k_lo]
  __shared__ u16 pfr[4][2][64][8];     // per-wave P A-frags

  const int b    = blockIdx.x >> 6;
  const int row0 = (blockIdx.x & 63) * 64;
  const int tid  = threadIdx.x;
  const int w    = tid >> 6;
  const int lane = tid & 63;
  const int g    = lane >> 4;          // 0..3
  const int c16  = lane & 15;

  const float mean = *meanp;

  // ---- Q A-frags (split bf16: A1=[q_hi|q_lo], A2=[q_hi|0]) ----
  float qv[16];
  {
    const float* qrow = qT + ((size_t)b*4096 + row0 + 16*w + c16) * 16;
#pragma unroll
    for (int i = 0; i < 4; ++i) {
      float4 t4 = reinterpret_cast<const float4*>(qrow)[i];
      qv[4*i] = t4.x; qv[4*i+1] = t4.y; qv[4*i+2] = t4.z; qv[4*i+3] = t4.w;
    }
  }
  u16 qhi[16], qlo[16];
#pragma unroll
  for (int i = 0; i < 16; ++i) {
    __hip_bfloat16 h = __float2bfloat16(qv[i]);
    float fh = __bfloat162float(h);
    __hip_bfloat16 lo = __float2bfloat16(qv[i] - fh);
    qhi[i] = __builtin_bit_cast(u16, h);
    qlo[i] = __builtin_bit_cast(u16, lo);
  }
  us8 a1u, a2u;
  {
    const bool koff8  = (g & 1);
    const bool lo_src = (g >= 2);
#pragma unroll
    for (int i = 0; i < 8; ++i) {
      u16 hs = koff8 ? qhi[i+8] : qhi[i];
      u16 ls = koff8 ? qlo[i+8] : qlo[i];
      a1u[i] = lo_src ? ls : hs;
      a2u[i] = lo_src ? (u16)0 : hs;
    }
  }
  const bf16x8 A1 = __builtin_bit_cast(bf16x8, a1u);
  const bf16x8 A2 = __builtin_bit_cast(bf16x8, a2u);

  f32x4 O[16];
#pragma unroll
  for (int i = 0; i < 16; ++i) O[i] = (f32x4){0.f, 0.f, 0.f, 0.f};
  float Lr[4] = {0.f, 0.f, 0.f, 0.f};
  float M = 0.0f;

  // K staging params for this thread
  const int kv_s = tid >> 2, t4v = tid & 3;
  const int ks = kv_s >> 4, kld0 = (kv_s & 15) + 16*(t4v >> 1), ki0 = 4*(t4v & 1);

  // ---- prologue: stage tile 0 ----
  {
    const u16* vsrc = vT + (size_t)b*256*4096;
#pragma unroll
    for (int i = 0; i < 8; ++i) {
      int u = i*256 + tid;
      int row = u >> 3, slot = u & 7;
      int sb = (slot*16) ^ ((row & 7) << 4);
      gl2lds16((const char*)(vsrc + (size_t)row*4096) + sb, (char*)&vbuf[0][0] + u*16);
    }
    float4 kvec = *reinterpret_cast<const float4*>(kT + ((size_t)b*4096 + kv_s)*16 + 4*t4v);
    float kf[4] = {kvec.x, kvec.y, kvec.z, kvec.w};
    us4 h4, l4;
#pragma unroll
    for (int di = 0; di < 4; ++di) {
      __hip_bfloat16 h = __float2bfloat16(kf[di]);
      float fh = __bfloat162float(h);
      __hip_bfloat16 lo = __float2bfloat16(kf[di] - fh);
      h4[di] = __builtin_bit_cast(u16, h);
      l4[di] = __builtin_bit_cast(u16, lo);
    }
    *reinterpret_cast<us4*>(&kfh[0][ks][kld0][ki0])    = h4;
    *reinterpret_cast<us4*>(&kfh[0][ks][kld0+32][ki0]) = h4;
    *reinterpret_cast<us4*>(&kfl[0][ks][kld0][ki0])    = l4;
    *reinterpret_cast<us4*>(&kfl[0][ks][kld0+32][ki0]) = l4;
  }
  __syncthreads();

  // ---- main loop over 64 KV tiles of 64 ----
  for (int t = 0; t < 64; ++t) {
    const int cur = t & 1, nxt = cur ^ 1;
    const int kv0n = ((t + 1) & 63) * 64;

    // [D] issue next-tile staging (K -> regs, V -> LDS via DMA)
    float4 kvec = *reinterpret_cast<const float4*>(kT + ((size_t)b*4096 + kv0n + kv_s)*16 + 4*t4v);
    {
      const u16* vsrc = vT + (size_t)b*256*4096 + kv0n;
#pragma unroll
      for (int i = 0; i < 8; ++i) {
        int u = i*256 + tid;
        int row = u >> 3, slot = u & 7;
        int sb = (slot*16) ^ ((row & 7) << 4);
        gl2lds16((const char*)(vsrc + (size_t)row*4096) + sb, (char*)&vbuf[nxt][0] + u*16);
      }
    }

    // [A] scores: 4 kv-subtiles x 2 MFMA (split-bf16)
    f32x4 S[4];
#pragma unroll
    for (int s = 0; s < 4; ++s) {
      bf16x8 bh = __builtin_bit_cast(bf16x8, *reinterpret_cast<const us8*>(&kfh[cur][s][lane][0]));
      bf16x8 bl = __builtin_bit_cast(bf16x8, *reinterpret_cast<const us8*>(&kfl[cur][s][lane][0]));
      f32x4 acc = (f32x4){0.f, 0.f, 0.f, 0.f};
      acc = __builtin_amdgcn_mfma_f32_16x16x32_bf16(A1, bh, acc, 0, 0, 0);
      acc = __builtin_amdgcn_mfma_f32_16x16x32_bf16(A2, bl, acc, 0, 0, 0);
      S[s] = acc;
    }

    // [B] mask + deferred-max online softmax (wave-wide M, THR=8)
    float pmax = -1e30f;
#pragma unroll
    for (int s = 0; s < 4; ++s)
#pragma unroll
      for (int r = 0; r < 4; ++r) {
        float v = S[s][r];
        v = (v < mean) ? 0.f : v;
        S[s][r] = v;
        pmax = fmaxf(pmax, v);
      }
    if (!__all(pmax <= M + 8.0f)) {
      float mw = pmax;
#pragma unroll
      for (int off = 1; off < 64; off <<= 1) mw = fmaxf(mw, __shfl_xor(mw, off));
      float Mn = fmaxf(M, mw);
      float sc = __expf(M - Mn);
#pragma unroll
      for (int i = 0; i < 16; ++i) {
        O[i][0] *= sc; O[i][1] *= sc; O[i][2] *= sc; O[i][3] *= sc;
      }
#pragma unroll
      for (int r = 0; r < 4; ++r) Lr[r] *= sc;
      M = Mn;
    }
    u16 pb[4][4];
#pragma unroll
    for (int s = 0; s < 4; ++s)
#pragma unroll
      for (int r = 0; r < 4; ++r) {
        float p = __expf(S[s][r] - M);
        Lr[r] += p;
        pb[s][r] = __builtin_bit_cast(u16, __float2bfloat16(p));
      }

    // [C] write P into A-frag layout: value(q'=4g+r, kv'=16s+c16) -> pfr[w][s>>1][q'+16*((kv'>>3)&3)][kv'&7]
    {
      const int ib = lane & 7;
      const int t1 = (lane >> 3) & 1;
#pragma unroll
      for (int s = 0; s < 4; ++s) {
        const int c2 = s >> 1;
        const int ldb = 16 * ((2*s + t1) & 3) + 4*g;
#pragma unroll
        for (int r = 0; r < 4; ++r) pfr[w][c2][ldb + r][ib] = pb[s][r];
      }
    }
    asm volatile("s_waitcnt lgkmcnt(0)" ::: "memory");
    __builtin_amdgcn_sched_barrier(0);

    // [G] PV: 2 k-chunks x 16 c-subtiles
#pragma unroll
    for (int c2 = 0; c2 < 2; ++c2) {
      bf16x8 pa = __builtin_bit_cast(bf16x8, *reinterpret_cast<const us8*>(&pfr[w][c2][lane][0]));
#pragma unroll
      for (int ct = 0; ct < 16; ++ct) {
        int row = ct*16 + c16;
        int off = (c2*64 + g*16) ^ ((lane & 7) << 4);
        bf16x8 vb = __builtin_bit_cast(bf16x8,
            *reinterpret_cast<const us8*>((const char*)&vbuf[cur][0] + row*128 + off));
        O[ct] = __builtin_amdgcn_mfma_f32_16x16x32_bf16(pa, vb, O[ct], 0, 0, 0);
      }
    }

    // [H] convert + write K frags for next tile
    {
      float kf[4] = {kvec.x, kvec.y, kvec.z, kvec.w};
      us4 h4, l4;
#pragma unroll
      for (int di = 0; di < 4; ++di) {
        __hip_bfloat16 h = __float2bfloat16(kf[di]);
        float fh = __bfloat162float(h);
        __hip_bfloat16 lo = __float2bfloat16(kf[di] - fh);
        h4[di] = __builtin_bit_cast(u16, h);
        l4[di] = __builtin_bit_cast(u16, lo);
      }
      *reinterpret_cast<us4*>(&kfh[nxt][ks][kld0][ki0])    = h4;
      *reinterpret_cast<us4*>(&kfh[nxt][ks][kld0+32][ki0]) = h4;
      *reinterpret_cast<us4*>(&kfl[nxt][ks][kld0][ki0])    = l4;
      *reinterpret_cast<us4*>(&kfl[nxt][ks][kld0+32][ki0]) = l4;
    }

    __syncthreads();
  }

  // ---- epilogue: reduce L across the 16 kv-lanes, write O/L to ods [b][c][n] ----
#pragma unroll
  for (int r = 0; r < 4; ++r) {
    float v = Lr[r];
#pragma unroll
    for (int off = 1; off < 16; off <<= 1) v += __shfl_xor(v, off);
    Lr[r] = v;
  }
  float inv[4];
#pragma unroll
  for (int r = 0; r < 4; ++r) inv[r] = 1.0f / Lr[r];
#pragma unroll
  for (int ct = 0; ct < 16; ++ct) {
    int c = ct*16 + c16;
    float* dst = ods + ((size_t)b*256 + c) * 4096u + row0 + 16*w + 4*g;
    float4 o4 = make_float4(O[ct][0]*inv[0], O[ct][1]*inv[1], O[ct][2]*inv[2], O[ct][3]*inv[3]);
    *reinterpret_cast<float4*>(dst) = o4;
  }
}

// ---------------- bilinear 4x upsample (half-pixel, edge clamp) + residual ----------------
// ods now [b][c][n=64x64] -> contiguous reads
__global__ __launch_bounds__(256) void k_up(const float* __restrict__ ods, const float* __restrict__ x,
                                            float* __restrict__ out) {
  size_t idx = (size_t)blockIdx.x * 256u + threadIdx.x;
  int j = (int)(idx & 255u);
  int i = (int)((idx >> 8) & 255u);
  size_t bc = idx >> 16;         // b*256 + c

  float py = (i + 0.5f) * 0.25f - 0.5f;
  float y0f = floorf(py);
  float wy = py - y0f;
  int y0 = (int)y0f, y1 = y0 + 1;
  y0 = max(y0, 0); y1 = min(y1, 63);

  float px = (j + 0.5f) * 0.25f - 0.5f;
  float x0f = floorf(px);
  float wx = px - x0f;
  int x0 = (int)x0f, x1 = x0 + 1;
  x0 = max(x0, 0); x1 = min(x1, 63);

  const float* gbase = ods + bc * 4096u;
  float g00 = gbase[y0 * 64 + x0];
  float g01 = gbase[y0 * 64 + x1];
  float g10 = gbase[y1 * 64 + x0];
  float g11 = gbase[y1 * 64 + x1];
  float val = (1.f - wy) * ((1.f - wx) * g00 + wx * g01) + wy * ((1.f - wx) * g10 + wx * g11);
  out[idx] = val + x[idx];
}

extern "C" void kernel_launch(void* const* d_in, const int* in_sizes, int n_in,
                              void* d_out, int out_size, void* d_ws, size_t ws_size,
                              hipStream_t stream) {
  const float* x  = (const float*)d_in[0];
  const float* Wq = (const float*)d_in[1];
  const float* bq = (const float*)d_in[2];
  const float* Wk = (const float*)d_in[3];
  const float* bk = (const float*)d_in[4];
  const float* Wv = (const float*)d_in[5];
  const float* bv = (const float*)d_in[6];
  float* out = (float*)d_out;

  char* ws = (char*)d_ws;
  float* xd   = (float*)(ws + OFF_XD);
  float* qT   = (float*)(ws + OFF_QT);
  float* kT   = (float*)(ws + OFF_KT);
  u16*   vT   = (u16*)(ws + OFF_VT);
  float* Sq   = (float*)(ws + OFF_SQ);
  float* Sk   = (float*)(ws + OFF_SK);
  float* mnp  = (float*)(ws + OFF_MEAN);
  float* ods  = xd;   // out_ds [b][c][n] aliases xd (xd dead after k_qk/k_v)

  k_maxpool<<<dim3(16384), dim3(256), 0, stream>>>(x, xd);
  k_qk<<<dim3(256), dim3(512), 0, stream>>>(xd, Wq, bq, Wk, bk, qT, kT);
  k_v<<<dim3(256), dim3(256), 0, stream>>>(xd, Wv, bv, vT);
  k_sum<<<dim3(64), dim3(64), 0, stream>>>(qT, kT, Sq, Sk);
  k_mean<<<dim3(1), dim3(64), 0, stream>>>(Sq, Sk, mnp);
  k_flash<<<dim3(256), dim3(256), 0, stream>>>(qT, kT, vT, mnp, ods);
  k_up<<<dim3(262144), dim3(256), 0, stream>>>(ods, x, out);
}

// Round 4
// 337.358 us; speedup vs baseline: 5.3363x; 1.2073x over previous
//
#include <hip/hip_runtime.h>
#include <hip/hip_bf16.h>
#include <cmath>
#include <cstdint>
#include <cstddef>

// Problem constants: B=4, C=256, H=W=256, DS=4 -> h=w=64, N=4096, Cq=16
typedef unsigned short u16;
typedef __attribute__((ext_vector_type(8))) __bf16 bf16x8;
typedef __attribute__((ext_vector_type(4))) float f32x4;
typedef __attribute__((ext_vector_type(8))) unsigned short us8;
typedef __attribute__((ext_vector_type(4))) unsigned short us4;

// Workspace layout (bytes)
static const size_t OFF_XD   = 0;            // [B][C][4096] fp32, 16 MB (aliased by out_ds [b][c][n])
static const size_t OFF_QT   = 16777216;     // [B][4096][16] fp32, 1 MB
static const size_t OFF_KT   = 17825792;     // [B][4096][16] fp32, 1 MB
static const size_t OFF_VT   = 18874368;     // [B][256][4096] bf16 (V transposed), 8 MB
static const size_t OFF_SQ   = 27262976;     // 64 floats
static const size_t OFF_SK   = 27263232;     // 64 floats
static const size_t OFF_MEAN = 27263488;     // 1 float

__device__ __forceinline__ void gl2lds16(const void* gsrc, void* ldst) {
  __builtin_amdgcn_global_load_lds(
      (const __attribute__((address_space(1))) unsigned int*)gsrc,
      (__attribute__((address_space(3))) unsigned int*)ldst, 16, 0, 0);
}

// ---------------- maxpool 4x4 ----------------
__global__ __launch_bounds__(256) void k_maxpool(const float* __restrict__ x,
                                                 float* __restrict__ xd) {
  unsigned idx = blockIdx.x * 256u + threadIdx.x;      // < 4*256*64*64
  unsigned xo = idx & 63u;
  unsigned yo = (idx >> 6) & 63u;
  unsigned bc = idx >> 12;                             // b*256 + c
  const float* base = x + (size_t)bc * 65536u + yo * 1024u + xo * 4u;
  float m = -1e30f;
#pragma unroll
  for (int dy = 0; dy < 4; ++dy) {
    float4 v = *reinterpret_cast<const float4*>(base + dy * 256);
    m = fmaxf(m, fmaxf(fmaxf(v.x, v.y), fmaxf(v.z, v.w)));
  }
  xd[(size_t)bc * 4096u + yo * 64u + xo] = m;
}

// ---------------- q,k 1x1 convs (C=256 -> 16), outputs [B][N][16] ----------------
__global__ __launch_bounds__(512) void k_qk(const float* __restrict__ xd,
                                            const float* __restrict__ Wq, const float* __restrict__ bq,
                                            const float* __restrict__ Wk, const float* __restrict__ bk,
                                            float* __restrict__ qT, float* __restrict__ kT) {
  __shared__ float smem[16896];   // union: xs[256][64] / part[8][64][33]
  float (*xs)[64] = reinterpret_cast<float(*)[64]>(smem);
  float (*part)[64][33] = reinterpret_cast<float(*)[64][33]>(smem);
  int b = blockIdx.x >> 6, n0 = (blockIdx.x & 63) * 64;
  int tid = threadIdx.x;
  {
    const float* src = xd + (size_t)b * 1048576u + n0;
#pragma unroll
    for (int i = 0; i < 8; ++i) {
      int l4 = tid + i * 512;
      int c = l4 >> 4, qq = l4 & 15;
      *reinterpret_cast<float4*>(&xs[c][qq * 4]) =
          *reinterpret_cast<const float4*>(src + (size_t)c * 4096u + qq * 4);
    }
  }
  __syncthreads();
  int nl = tid & 63, pp = tid >> 6;
  float qa[16], ka[16];
#pragma unroll
  for (int o = 0; o < 16; ++o) { qa[o] = 0.f; ka[o] = 0.f; }
  for (int i = 0; i < 32; ++i) {
    int c = pp * 32 + i;
    float xv = xs[c][nl];
#pragma unroll
    for (int o = 0; o < 16; ++o) {
      qa[o] = fmaf(Wq[o * 256 + c], xv, qa[o]);
      ka[o] = fmaf(Wk[o * 256 + c], xv, ka[o]);
    }
  }
  __syncthreads();
#pragma unroll
  for (int o = 0; o < 16; ++o) {
    part[pp][nl][o]      = qa[o];
    part[pp][nl][16 + o] = ka[o];
  }
  __syncthreads();
#pragma unroll
  for (int i = 0; i < 4; ++i) {
    int idx = tid * 4 + i;
    int n = idx >> 5, o = idx & 31;
    float s = 0.f;
#pragma unroll
    for (int p = 0; p < 8; ++p) s += part[p][n][o];
    if (o < 16) qT[((size_t)b * 4096u + n0 + n) * 16u + o]        = s + bq[o];
    else        kT[((size_t)b * 4096u + n0 + n) * 16u + (o - 16)] = s + bk[o - 16];
  }
}

// ---------------- v 1x1 conv (256 -> 256), output V^T bf16 [B][256][4096] ----------------
__global__ __launch_bounds__(256) void k_v(const float* __restrict__ xd,
                                           const float* __restrict__ Wv, const float* __restrict__ bv,
                                           u16* __restrict__ vT) {
  __shared__ float xs[256][64];
  int b = blockIdx.x >> 6, nt = blockIdx.x & 63;
  int n0 = nt * 64;
  int tid = threadIdx.x;
  {
    const float* src = xd + (size_t)b * 1048576u + n0;
#pragma unroll
    for (int i = 0; i < 16; ++i) {
      int l4 = tid + i * 256;
      int c = l4 >> 4, q = l4 & 15;
      *reinterpret_cast<float4*>(&xs[c][q * 4]) =
          *reinterpret_cast<const float4*>(src + (size_t)c * 4096u + q * 4);
    }
  }
  __syncthreads();
  int ci = tid >> 4, ni = tid & 15;
  float acc[16][4];
#pragma unroll
  for (int j = 0; j < 16; ++j) { acc[j][0]=0.f; acc[j][1]=0.f; acc[j][2]=0.f; acc[j][3]=0.f; }
  for (int cc4 = 0; cc4 < 64; ++cc4) {
    float4 xv0 = *reinterpret_cast<const float4*>(&xs[cc4*4+0][ni*4]);
    float4 xv1 = *reinterpret_cast<const float4*>(&xs[cc4*4+1][ni*4]);
    float4 xv2 = *reinterpret_cast<const float4*>(&xs[cc4*4+2][ni*4]);
    float4 xv3 = *reinterpret_cast<const float4*>(&xs[cc4*4+3][ni*4]);
#pragma unroll
    for (int j = 0; j < 16; ++j) {
      float4 wv = *reinterpret_cast<const float4*>(&Wv[(size_t)(ci*16 + j) * 256u + cc4*4]);
      acc[j][0] = fmaf(wv.x, xv0.x, fmaf(wv.y, xv1.x, fmaf(wv.z, xv2.x, fmaf(wv.w, xv3.x, acc[j][0]))));
      acc[j][1] = fmaf(wv.x, xv0.y, fmaf(wv.y, xv1.y, fmaf(wv.z, xv2.y, fmaf(wv.w, xv3.y, acc[j][1]))));
      acc[j][2] = fmaf(wv.x, xv0.z, fmaf(wv.y, xv1.z, fmaf(wv.z, xv2.z, fmaf(wv.w, xv3.z, acc[j][2]))));
      acc[j][3] = fmaf(wv.x, xv0.w, fmaf(wv.y, xv1.w, fmaf(wv.z, xv2.w, fmaf(wv.w, xv3.w, acc[j][3]))));
    }
  }
#pragma unroll
  for (int j = 0; j < 16; ++j) {
    int c = ci*16 + j;
    float bb = bv[c];
    us4 u;
#pragma unroll
    for (int nn = 0; nn < 4; ++nn)
      u[nn] = __builtin_bit_cast(u16, __float2bfloat16(acc[j][nn] + bb));
    *reinterpret_cast<us4*>(vT + ((size_t)b*256 + c) * 4096u + n0 + ni*4) = u;
  }
}

// ---------------- per-(b,o) column sums of q,k ----------------
__global__ __launch_bounds__(64) void k_sum(const float* __restrict__ qT, const float* __restrict__ kT,
                                            float* __restrict__ Sq, float* __restrict__ Sk) {
  int b = blockIdx.x >> 4, o = blockIdx.x & 15;
  int t = threadIdx.x;
  float sq = 0.f, sk = 0.f;
  for (int n = t; n < 4096; n += 64) {
    sq += qT[((size_t)b * 4096u + n) * 16u + o];
    sk += kT[((size_t)b * 4096u + n) * 16u + o];
  }
#pragma unroll
  for (int off = 32; off > 0; off >>= 1) {
    sq += __shfl_down(sq, off);
    sk += __shfl_down(sk, off);
  }
  if (t == 0) { Sq[blockIdx.x] = sq; Sk[blockIdx.x] = sk; }
}

__global__ __launch_bounds__(64) void k_mean(const float* __restrict__ Sq, const float* __restrict__ Sk,
                                             float* __restrict__ meanp) {
  int t = threadIdx.x;
  float p = Sq[t] * Sk[t];
#pragma unroll
  for (int off = 32; off > 0; off >>= 1) p += __shfl_down(p, off);
  if (t == 0) *meanp = p * (1.0f / 67108864.0f);   // / (B*N*N)
}

// ---------------- one-pass MFMA flash: split-bf16 QK^T + masked softmax + PV ----------------
// 256 blocks (b x 64 q-tiles), 512 threads = 8 waves (2/SIMD).
// wave w: q-row block wq=w&3 (rows 16wq..16wq+16), c-half wc=w>>2 (PV cols wc*128..+128).
// QK^T/softmax duplicated across wc (deterministic); PV split -> O regs halved.
__global__ __launch_bounds__(512) void k_flash(const float* __restrict__ qT,
                                               const float* __restrict__ kT,
                                               const u16* __restrict__ vT,
                                               const float* __restrict__ meanp,
                                               float* __restrict__ ods) {
  __shared__ u16 vbuf[2][16384];       // [buf][c row(256) x kv(64)] linear, source-swizzled (64 KB)
  __shared__ u16 kfh[2][4][64][8];     // B-frag [k_hi|k_hi], fragment-linear (8 KB)
  __shared__ u16 kfl[2][4][64][8];     // B-frag [k_lo|k_lo] (8 KB)
  __shared__ u16 pfr[8][2][64][8];     // per-wave P A-frags (16 KB)

  const int b    = blockIdx.x >> 6;
  const int row0 = (blockIdx.x & 63) * 64;
  const int tid  = threadIdx.x;
  const int w    = tid >> 6;
  const int lane = tid & 63;
  const int wq   = w & 3;
  const int wc   = w >> 2;
  const int g    = lane >> 4;          // 0..3
  const int c16  = lane & 15;

  const float mean = *meanp;

  // ---- Q A-frags (split bf16: A1=[q_hi|q_lo], A2=[q_hi|0]) ----
  float qv[16];
  {
    const float* qrow = qT + ((size_t)b*4096 + row0 + 16*wq + c16) * 16;
#pragma unroll
    for (int i = 0; i < 4; ++i) {
      float4 t4 = reinterpret_cast<const float4*>(qrow)[i];
      qv[4*i] = t4.x; qv[4*i+1] = t4.y; qv[4*i+2] = t4.z; qv[4*i+3] = t4.w;
    }
  }
  u16 qhi[16], qlo[16];
#pragma unroll
  for (int i = 0; i < 16; ++i) {
    __hip_bfloat16 h = __float2bfloat16(qv[i]);
    float fh = __bfloat162float(h);
    __hip_bfloat16 lo = __float2bfloat16(qv[i] - fh);
    qhi[i] = __builtin_bit_cast(u16, h);
    qlo[i] = __builtin_bit_cast(u16, lo);
  }
  us8 a1u, a2u;
  {
    const bool koff8  = (g & 1);
    const bool lo_src = (g >= 2);
#pragma unroll
    for (int i = 0; i < 8; ++i) {
      u16 hs = koff8 ? qhi[i+8] : qhi[i];
      u16 ls = koff8 ? qlo[i+8] : qlo[i];
      a1u[i] = lo_src ? ls : hs;
      a2u[i] = lo_src ? (u16)0 : hs;
    }
  }
  const bf16x8 A1 = __builtin_bit_cast(bf16x8, a1u);
  const bf16x8 A2 = __builtin_bit_cast(bf16x8, a2u);

  f32x4 O[8];
#pragma unroll
  for (int i = 0; i < 8; ++i) O[i] = (f32x4){0.f, 0.f, 0.f, 0.f};
  float Lr[4] = {0.f, 0.f, 0.f, 0.f};
  float M = 0.0f;

  // K staging params (threads 0..255 only)
  const int kv_s = tid >> 2, t4v = tid & 3;
  const int ks = kv_s >> 4, kld0 = (kv_s & 15) + 16*(t4v >> 1), ki0 = 4*(t4v & 1);

  // ---- prologue: stage tile 0 ----
  {
    const u16* vsrc = vT + (size_t)b*256*4096;
#pragma unroll
    for (int i = 0; i < 4; ++i) {
      int u = i*512 + tid;
      int row = u >> 3, slot = u & 7;
      int sb = (slot*16) ^ ((row & 7) << 4);
      gl2lds16((const char*)(vsrc + (size_t)row*4096) + sb, (char*)&vbuf[0][0] + u*16);
    }
    if (tid < 256) {
      float4 kvec = *reinterpret_cast<const float4*>(kT + ((size_t)b*4096 + kv_s)*16 + 4*t4v);
      float kf[4] = {kvec.x, kvec.y, kvec.z, kvec.w};
      us4 h4, l4;
#pragma unroll
      for (int di = 0; di < 4; ++di) {
        __hip_bfloat16 h = __float2bfloat16(kf[di]);
        float fh = __bfloat162float(h);
        __hip_bfloat16 lo = __float2bfloat16(kf[di] - fh);
        h4[di] = __builtin_bit_cast(u16, h);
        l4[di] = __builtin_bit_cast(u16, lo);
      }
      *reinterpret_cast<us4*>(&kfh[0][ks][kld0][ki0])    = h4;
      *reinterpret_cast<us4*>(&kfh[0][ks][kld0+32][ki0]) = h4;
      *reinterpret_cast<us4*>(&kfl[0][ks][kld0][ki0])    = l4;
      *reinterpret_cast<us4*>(&kfl[0][ks][kld0+32][ki0]) = l4;
    }
  }
  __syncthreads();

  // ---- main loop over 64 KV tiles of 64 ----
  for (int t = 0; t < 64; ++t) {
    const int cur = t & 1, nxt = cur ^ 1;
    const int kv0n = ((t + 1) & 63) * 64;

    // [D] issue next-tile staging (K -> regs, V -> LDS via DMA)
    float4 kvec;
    if (tid < 256)
      kvec = *reinterpret_cast<const float4*>(kT + ((size_t)b*4096 + kv0n + kv_s)*16 + 4*t4v);
    {
      const u16* vsrc = vT + (size_t)b*256*4096 + kv0n;
#pragma unroll
      for (int i = 0; i < 4; ++i) {
        int u = i*512 + tid;
        int row = u >> 3, slot = u & 7;
        int sb = (slot*16) ^ ((row & 7) << 4);
        gl2lds16((const char*)(vsrc + (size_t)row*4096) + sb, (char*)&vbuf[nxt][0] + u*16);
      }
    }

    // [A] scores: 4 kv-subtiles x 2 MFMA (split-bf16)
    f32x4 S[4];
#pragma unroll
    for (int s = 0; s < 4; ++s) {
      bf16x8 bh = __builtin_bit_cast(bf16x8, *reinterpret_cast<const us8*>(&kfh[cur][s][lane][0]));
      bf16x8 bl = __builtin_bit_cast(bf16x8, *reinterpret_cast<const us8*>(&kfl[cur][s][lane][0]));
      f32x4 acc = (f32x4){0.f, 0.f, 0.f, 0.f};
      acc = __builtin_amdgcn_mfma_f32_16x16x32_bf16(A1, bh, acc, 0, 0, 0);
      acc = __builtin_amdgcn_mfma_f32_16x16x32_bf16(A2, bl, acc, 0, 0, 0);
      S[s] = acc;
    }

    // [B] mask + deferred-max online softmax (wave-wide M, THR=8)
    float pmax = -1e30f;
#pragma unroll
    for (int s = 0; s < 4; ++s)
#pragma unroll
      for (int r = 0; r < 4; ++r) {
        float v = S[s][r];
        v = (v < mean) ? 0.f : v;
        S[s][r] = v;
        pmax = fmaxf(pmax, v);
      }
    if (!__all(pmax <= M + 8.0f)) {
      float mw = pmax;
#pragma unroll
      for (int off = 1; off < 64; off <<= 1) mw = fmaxf(mw, __shfl_xor(mw, off));
      float Mn = fmaxf(M, mw);
      float sc = __expf(M - Mn);
#pragma unroll
      for (int i = 0; i < 8; ++i) {
        O[i][0] *= sc; O[i][1] *= sc; O[i][2] *= sc; O[i][3] *= sc;
      }
#pragma unroll
      for (int r = 0; r < 4; ++r) Lr[r] *= sc;
      M = Mn;
    }
    u16 pb[4][4];
#pragma unroll
    for (int s = 0; s < 4; ++s)
#pragma unroll
      for (int r = 0; r < 4; ++r) {
        float p = __expf(S[s][r] - M);
        Lr[r] += p;
        pb[s][r] = __builtin_bit_cast(u16, __float2bfloat16(p));
      }

    // [C] write P into per-wave A-frag copy
    {
      const int ib = lane & 7;
      const int t1 = (lane >> 3) & 1;
#pragma unroll
      for (int s = 0; s < 4; ++s) {
        const int c2 = s >> 1;
        const int ldb = 16 * ((2*s + t1) & 3) + 4*g;
#pragma unroll
        for (int r = 0; r < 4; ++r) pfr[w][c2][ldb + r][ib] = pb[s][r];
      }
    }
    asm volatile("s_waitcnt lgkmcnt(0)" ::: "memory");
    __builtin_amdgcn_sched_barrier(0);

    // [G] PV: 2 k-chunks x 8 c-subtiles (this wave's c-half)
#pragma unroll
    for (int c2 = 0; c2 < 2; ++c2) {
      bf16x8 pa = __builtin_bit_cast(bf16x8, *reinterpret_cast<const us8*>(&pfr[w][c2][lane][0]));
#pragma unroll
      for (int ct = 0; ct < 8; ++ct) {
        int row = (wc*8 + ct)*16 + c16;
        int off = (c2*64 + g*16) ^ ((lane & 7) << 4);
        bf16x8 vb = __builtin_bit_cast(bf16x8,
            *reinterpret_cast<const us8*>((const char*)&vbuf[cur][0] + row*128 + off));
        O[ct] = __builtin_amdgcn_mfma_f32_16x16x32_bf16(pa, vb, O[ct], 0, 0, 0);
      }
    }

    // [H] convert + write K frags for next tile
    if (tid < 256) {
      float kf[4] = {kvec.x, kvec.y, kvec.z, kvec.w};
      us4 h4, l4;
#pragma unroll
      for (int di = 0; di < 4; ++di) {
        __hip_bfloat16 h = __float2bfloat16(kf[di]);
        float fh = __bfloat162float(h);
        __hip_bfloat16 lo = __float2bfloat16(kf[di] - fh);
        h4[di] = __builtin_bit_cast(u16, h);
        l4[di] = __builtin_bit_cast(u16, lo);
      }
      *reinterpret_cast<us4*>(&kfh[nxt][ks][kld0][ki0])    = h4;
      *reinterpret_cast<us4*>(&kfh[nxt][ks][kld0+32][ki0]) = h4;
      *reinterpret_cast<us4*>(&kfl[nxt][ks][kld0][ki0])    = l4;
      *reinterpret_cast<us4*>(&kfl[nxt][ks][kld0+32][ki0]) = l4;
    }

    __syncthreads();
  }

  // ---- epilogue: reduce L across the 16 kv-lanes, write O/L to ods [b][c][n] ----
#pragma unroll
  for (int r = 0; r < 4; ++r) {
    float v = Lr[r];
#pragma unroll
    for (int off = 1; off < 16; off <<= 1) v += __shfl_xor(v, off);
    Lr[r] = v;
  }
  float inv[4];
#pragma unroll
  for (int r = 0; r < 4; ++r) inv[r] = 1.0f / Lr[r];
#pragma unroll
  for (int ct = 0; ct < 8; ++ct) {
    int c = (wc*8 + ct)*16 + c16;
    float* dst = ods + ((size_t)b*256 + c) * 4096u + row0 + 16*wq + 4*g;
    float4 o4 = make_float4(O[ct][0]*inv[0], O[ct][1]*inv[1], O[ct][2]*inv[2], O[ct][3]*inv[3]);
    *reinterpret_cast<float4*>(dst) = o4;
  }
}

// ---------------- bilinear 4x upsample + residual, 4 px/thread ----------------
// ods [b][c][64x64]. Fixed horizontal weights per 4-strip; float4 x/out.
__global__ __launch_bounds__(256) void k_up(const float* __restrict__ ods, const float* __restrict__ x,
                                            float* __restrict__ out) {
  unsigned idx4 = blockIdx.x * 256u + threadIdx.x;   // < 16777216
  int a  = (int)(idx4 & 63u);          // horizontal cell = output j strip [4a,4a+4)
  int i  = (int)((idx4 >> 6) & 255u);  // output row
  size_t bc = idx4 >> 14;              // b*256 + c

  float py = (i + 0.5f) * 0.25f - 0.5f;
  float y0f = floorf(py);
  float wy = py - y0f;
  int y0 = (int)y0f, y1 = y0 + 1;
  y0 = max(y0, 0); y1 = min(y1, 63);

  int xm1 = max(a - 1, 0), xp1 = min(a + 1, 63);

  const float* r0 = ods + bc * 4096u + y0 * 64;
  const float* r1 = ods + bc * 4096u + y1 * 64;
  float wy1 = 1.f - wy;
  float vm1 = wy1 * r0[xm1] + wy * r1[xm1];
  float v0  = wy1 * r0[a]   + wy * r1[a];
  float vp1 = wy1 * r0[xp1] + wy * r1[xp1];

  float4 xv = *reinterpret_cast<const float4*>(x + (size_t)idx4 * 4u);
  float4 o4;
  o4.x = fmaf(0.375f, vm1, 0.625f * v0) + xv.x;
  o4.y = fmaf(0.125f, vm1, 0.875f * v0) + xv.y;
  o4.z = fmaf(0.875f, v0, 0.125f * vp1) + xv.z;
  o4.w = fmaf(0.625f, v0, 0.375f * vp1) + xv.w;
  *reinterpret_cast<float4*>(out + (size_t)idx4 * 4u) = o4;
}

extern "C" void kernel_launch(void* const* d_in, const int* in_sizes, int n_in,
                              void* d_out, int out_size, void* d_ws, size_t ws_size,
                              hipStream_t stream) {
  const float* x  = (const float*)d_in[0];
  const float* Wq = (const float*)d_in[1];
  const float* bq = (const float*)d_in[2];
  const float* Wk = (const float*)d_in[3];
  const float* bk = (const float*)d_in[4];
  const float* Wv = (const float*)d_in[5];
  const float* bv = (const float*)d_in[6];
  float* out = (float*)d_out;

  char* ws = (char*)d_ws;
  float* xd   = (float*)(ws + OFF_XD);
  float* qT   = (float*)(ws + OFF_QT);
  float* kT   = (float*)(ws + OFF_KT);
  u16*   vT   = (u16*)(ws + OFF_VT);
  float* Sq   = (float*)(ws + OFF_SQ);
  float* Sk   = (float*)(ws + OFF_SK);
  float* mnp  = (float*)(ws + OFF_MEAN);
  float* ods  = xd;   // out_ds [b][c][n] aliases xd (xd dead after k_qk/k_v)

  k_maxpool<<<dim3(16384), dim3(256), 0, stream>>>(x, xd);
  k_qk<<<dim3(256), dim3(512), 0, stream>>>(xd, Wq, bq, Wk, bk, qT, kT);
  k_v<<<dim3(256), dim3(256), 0, stream>>>(xd, Wv, bv, vT);
  k_sum<<<dim3(64), dim3(64), 0, stream>>>(qT, kT, Sq, Sk);
  k_mean<<<dim3(1), dim3(64), 0, stream>>>(Sq, Sk, mnp);
  k_flash<<<dim3(256), dim3(512), 0, stream>>>(qT, kT, vT, mnp, ods);
  k_up<<<dim3(65536), dim3(256), 0, stream>>>(ods, x, out);
}

// Round 5
// 297.703 us; speedup vs baseline: 6.0471x; 1.1332x over previous
//
#include <hip/hip_runtime.h>
#include <hip/hip_bf16.h>
#include <cmath>
#include <cstdint>
#include <cstddef>

// Problem constants: B=4, C=256, H=W=256, DS=4 -> h=w=64, N=4096, Cq=16
typedef unsigned short u16;
typedef __attribute__((ext_vector_type(8))) __bf16 bf16x8;
typedef __attribute__((ext_vector_type(4))) float f32x4;
typedef __attribute__((ext_vector_type(8))) unsigned short us8;
typedef __attribute__((ext_vector_type(4))) unsigned short us4;

// Workspace layout (bytes)
static const size_t OFF_ODS   = 0;            // [B][C][4096] fp32 out_ds, 16 MB
static const size_t OFF_QT    = 16777216;     // [B][4096][16] fp32, 1 MB
static const size_t OFF_KT    = 17825792;     // [B][4096][16] fp32, 1 MB
static const size_t OFF_VT    = 18874368;     // [B][256][4096] bf16 (V transposed), 8 MB
static const size_t OFF_SPART = 27262976;     // [256 blocks][32] fp32 partial col-sums, 32 KB
static const size_t OFF_MEAN  = 27295744;     // 1 float

__device__ __forceinline__ void gl2lds16(const void* gsrc, void* ldst) {
  __builtin_amdgcn_global_load_lds(
      (const __attribute__((address_space(1))) unsigned int*)gsrc,
      (__attribute__((address_space(3))) unsigned int*)ldst, 16, 0, 0);
}

// ---------------- fused maxpool + q/k/v 1x1 convs + per-block column sums ----------------
// 256 blocks (b x 64 row-strips of 64 tokens), 512 threads.
// Reads x[b,:,4yo:4yo+4,:] once; xd never touches HBM.
__global__ __launch_bounds__(512) void k_front(const float* __restrict__ x,
                                               const float* __restrict__ Wq, const float* __restrict__ bq,
                                               const float* __restrict__ Wk, const float* __restrict__ bk,
                                               const float* __restrict__ Wv, const float* __restrict__ bv,
                                               float* __restrict__ qT, float* __restrict__ kT,
                                               u16* __restrict__ vT, float* __restrict__ Spart) {
  __shared__ float smem[17408];   // union: xs[256][64] (16384) / part[8][64][33] (16896); red at +16896
  float (*xs)[64] = reinterpret_cast<float(*)[64]>(smem);
  float (*part)[64][33] = reinterpret_cast<float(*)[64][33]>(smem);
  float (*red)[32] = reinterpret_cast<float(*)[32]>(smem + 16896);
  const int b = blockIdx.x >> 6, yo = blockIdx.x & 63;
  const int n0 = yo * 64;
  const int tid = threadIdx.x;

  // ---- maxpool 4x4 of strip -> xs[c][xo] ----
  {
    const float* src = x + (size_t)b * 16777216u + (size_t)(4 * yo) * 256u;
#pragma unroll
    for (int i = 0; i < 32; ++i) {
      int u = i * 512 + tid;            // 0..16383
      int c = u >> 6, xo = u & 63;
      const float* p0 = src + (size_t)c * 65536u + xo * 4;
      float m = -1e30f;
#pragma unroll
      for (int r = 0; r < 4; ++r) {
        float4 v4 = *reinterpret_cast<const float4*>(p0 + r * 256);
        m = fmaxf(m, fmaxf(fmaxf(v4.x, v4.y), fmaxf(v4.z, v4.w)));
      }
      xs[c][xo] = m;
    }
  }
  __syncthreads();

  // ---- v conv: thread owns 8 out-channels x 4 tokens ----
  {
    const int ci = tid >> 4, ni = tid & 15;
    float vacc[8][4];
#pragma unroll
    for (int j = 0; j < 8; ++j) { vacc[j][0]=0.f; vacc[j][1]=0.f; vacc[j][2]=0.f; vacc[j][3]=0.f; }
    for (int cc4 = 0; cc4 < 64; ++cc4) {
      float4 xv0 = *reinterpret_cast<const float4*>(&xs[cc4*4+0][ni*4]);
      float4 xv1 = *reinterpret_cast<const float4*>(&xs[cc4*4+1][ni*4]);
      float4 xv2 = *reinterpret_cast<const float4*>(&xs[cc4*4+2][ni*4]);
      float4 xv3 = *reinterpret_cast<const float4*>(&xs[cc4*4+3][ni*4]);
#pragma unroll
      for (int j = 0; j < 8; ++j) {
        float4 wv = *reinterpret_cast<const float4*>(&Wv[(size_t)(ci*8 + j) * 256u + cc4*4]);
        vacc[j][0] = fmaf(wv.x, xv0.x, fmaf(wv.y, xv1.x, fmaf(wv.z, xv2.x, fmaf(wv.w, xv3.x, vacc[j][0]))));
        vacc[j][1] = fmaf(wv.x, xv0.y, fmaf(wv.y, xv1.y, fmaf(wv.z, xv2.y, fmaf(wv.w, xv3.y, vacc[j][1]))));
        vacc[j][2] = fmaf(wv.x, xv0.z, fmaf(wv.y, xv1.z, fmaf(wv.z, xv2.z, fmaf(wv.w, xv3.z, vacc[j][2]))));
        vacc[j][3] = fmaf(wv.x, xv0.w, fmaf(wv.y, xv1.w, fmaf(wv.z, xv2.w, fmaf(wv.w, xv3.w, vacc[j][3]))));
      }
    }
#pragma unroll
    for (int j = 0; j < 8; ++j) {
      int c = ci*8 + j;
      float bb = bv[c];
      us4 u;
#pragma unroll
      for (int nn = 0; nn < 4; ++nn)
        u[nn] = __builtin_bit_cast(u16, __float2bfloat16(vacc[j][nn] + bb));
      *reinterpret_cast<us4*>(vT + ((size_t)b*256 + c) * 4096u + n0 + ni*4) = u;
    }
  }

  // ---- q/k partials: thread owns token nl, c-range pp*32..+32 ----
  const int nl = tid & 63, pp = tid >> 6;
  float qa[16], ka[16];
#pragma unroll
  for (int o = 0; o < 16; ++o) { qa[o] = 0.f; ka[o] = 0.f; }
  for (int i = 0; i < 32; ++i) {
    int c = pp * 32 + i;
    float xv = xs[c][nl];
#pragma unroll
    for (int o = 0; o < 16; ++o) {
      qa[o] = fmaf(Wq[o * 256 + c], xv, qa[o]);
      ka[o] = fmaf(Wk[o * 256 + c], xv, ka[o]);
    }
  }
  __syncthreads();   // all xs reads done before part overwrite
#pragma unroll
  for (int o = 0; o < 16; ++o) {
    part[pp][nl][o]      = qa[o];
    part[pp][nl][16 + o] = ka[o];
  }
  __syncthreads();
  // final reduce -> qT/kT
#pragma unroll
  for (int i = 0; i < 4; ++i) {
    int idx = tid * 4 + i;
    int n = idx >> 5, o = idx & 31;
    float s = 0.f;
#pragma unroll
    for (int p = 0; p < 8; ++p) s += part[p][n][o];
    if (o < 16) qT[((size_t)b * 4096u + n0 + n) * 16u + o]        = s + bq[o];
    else        kT[((size_t)b * 4096u + n0 + n) * 16u + (o - 16)] = s + bk[o - 16];
  }
  // block column-sums (no bias; k_mean adds it) -> Spart[block][32]
  {
    int o = tid & 31, grp = tid >> 5;   // 16 grps x 4 tokens
    float s = 0.f;
#pragma unroll
    for (int nn = 0; nn < 4; ++nn) {
      int n = grp * 4 + nn;
#pragma unroll
      for (int p = 0; p < 8; ++p) s += part[p][n][o];
    }
    red[grp][o] = s;
  }
  __syncthreads();
  if (tid < 32) {
    float s = 0.f;
#pragma unroll
    for (int g = 0; g < 16; ++g) s += red[g][tid];
    Spart[(size_t)blockIdx.x * 32u + tid] = s;
  }
}

// ---------------- scalar mean of att from block partial sums ----------------
__global__ __launch_bounds__(64) void k_mean(const float* __restrict__ Spart,
                                             const float* __restrict__ bq, const float* __restrict__ bk,
                                             float* __restrict__ meanp) {
  int t = threadIdx.x;        // (b,o): b = t>>4, o = t&15
  int b = t >> 4, o = t & 15;
  float sq = 4096.0f * bq[o], sk = 4096.0f * bk[o];
  for (int blk = 0; blk < 64; ++blk) {
    const float* p = Spart + ((size_t)(b * 64 + blk)) * 32u;
    sq += p[o];
    sk += p[16 + o];
  }
  float pr = sq * sk;
#pragma unroll
  for (int off = 32; off > 0; off >>= 1) pr += __shfl_down(pr, off);
  if (t == 0) *meanp = pr * (1.0f / 67108864.0f);   // / (B*N*N)
}

// ---------------- one-pass MFMA flash: split-bf16 QK^T + masked softmax + PV ----------------
// 256 blocks, XCD-bijective remap: batch = bits1-2 of blockIdx -> each XCD serves ONE batch
// (2 MB V + 256 KB K fit its 4 MB L2). 512 threads = 8 waves (2/SIMD).
__global__ __launch_bounds__(512) void k_flash(const float* __restrict__ qT,
                                               const float* __restrict__ kT,
                                               const u16* __restrict__ vT,
                                               const float* __restrict__ meanp,
                                               float* __restrict__ ods) {
  __shared__ u16 vbuf[2][16384];       // [buf][c row(256) x kv(64)] linear, source-swizzled (64 KB)
  __shared__ u16 kfh[2][4][64][8];     // B-frag [k_hi|k_hi], fragment-linear (8 KB)
  __shared__ u16 kfl[2][4][64][8];     // B-frag [k_lo|k_lo] (8 KB)
  __shared__ u16 pfr[8][2][64][8];     // per-wave P A-frags (16 KB)

  const int orig = blockIdx.x;
  const int b    = (orig >> 1) & 3;                        // bits1-2 -> XCD pair per batch
  const int row0 = (((orig & 1) << 5) | (orig >> 3)) * 64; // bijective q-tile remap
  const int tid  = threadIdx.x;
  const int w    = tid >> 6;
  const int lane = tid & 63;
  const int wq   = w & 3;
  const int wc   = w >> 2;
  const int g    = lane >> 4;          // 0..3
  const int c16  = lane & 15;

  const float mean = *meanp;

  // ---- Q A-frags (split bf16: A1=[q_hi|q_lo], A2=[q_hi|0]) ----
  float qv[16];
  {
    const float* qrow = qT + ((size_t)b*4096 + row0 + 16*wq + c16) * 16;
#pragma unroll
    for (int i = 0; i < 4; ++i) {
      float4 t4 = reinterpret_cast<const float4*>(qrow)[i];
      qv[4*i] = t4.x; qv[4*i+1] = t4.y; qv[4*i+2] = t4.z; qv[4*i+3] = t4.w;
    }
  }
  u16 qhi[16], qlo[16];
#pragma unroll
  for (int i = 0; i < 16; ++i) {
    __hip_bfloat16 h = __float2bfloat16(qv[i]);
    float fh = __bfloat162float(h);
    __hip_bfloat16 lo = __float2bfloat16(qv[i] - fh);
    qhi[i] = __builtin_bit_cast(u16, h);
    qlo[i] = __builtin_bit_cast(u16, lo);
  }
  us8 a1u, a2u;
  {
    const bool koff8  = (g & 1);
    const bool lo_src = (g >= 2);
#pragma unroll
    for (int i = 0; i < 8; ++i) {
      u16 hs = koff8 ? qhi[i+8] : qhi[i];
      u16 ls = koff8 ? qlo[i+8] : qlo[i];
      a1u[i] = lo_src ? ls : hs;
      a2u[i] = lo_src ? (u16)0 : hs;
    }
  }
  const bf16x8 A1 = __builtin_bit_cast(bf16x8, a1u);
  const bf16x8 A2 = __builtin_bit_cast(bf16x8, a2u);

  f32x4 O[8];
#pragma unroll
  for (int i = 0; i < 8; ++i) O[i] = (f32x4){0.f, 0.f, 0.f, 0.f};
  float Lr[4] = {0.f, 0.f, 0.f, 0.f};
  float M = 0.0f;

  // K staging params (threads 0..255 only)
  const int kv_s = tid >> 2, t4v = tid & 3;
  const int ks = kv_s >> 4, kld0 = (kv_s & 15) + 16*(t4v >> 1), ki0 = 4*(t4v & 1);

  // ---- prologue: stage tile 0 ----
  {
    const u16* vsrc = vT + (size_t)b*256*4096;
#pragma unroll
    for (int i = 0; i < 4; ++i) {
      int u = i*512 + tid;
      int row = u >> 3, slot = u & 7;
      int sb = (slot*16) ^ ((row & 7) << 4);
      gl2lds16((const char*)(vsrc + (size_t)row*4096) + sb, (char*)&vbuf[0][0] + u*16);
    }
    if (tid < 256) {
      float4 kvec = *reinterpret_cast<const float4*>(kT + ((size_t)b*4096 + kv_s)*16 + 4*t4v);
      float kf[4] = {kvec.x, kvec.y, kvec.z, kvec.w};
      us4 h4, l4;
#pragma unroll
      for (int di = 0; di < 4; ++di) {
        __hip_bfloat16 h = __float2bfloat16(kf[di]);
        float fh = __bfloat162float(h);
        __hip_bfloat16 lo = __float2bfloat16(kf[di] - fh);
        h4[di] = __builtin_bit_cast(u16, h);
        l4[di] = __builtin_bit_cast(u16, lo);
      }
      *reinterpret_cast<us4*>(&kfh[0][ks][kld0][ki0])    = h4;
      *reinterpret_cast<us4*>(&kfh[0][ks][kld0+32][ki0]) = h4;
      *reinterpret_cast<us4*>(&kfl[0][ks][kld0][ki0])    = l4;
      *reinterpret_cast<us4*>(&kfl[0][ks][kld0+32][ki0]) = l4;
    }
  }
  __syncthreads();

  // ---- main loop over 64 KV tiles of 64 ----
  for (int t = 0; t < 64; ++t) {
    const int cur = t & 1, nxt = cur ^ 1;
    const int kv0n = ((t + 1) & 63) * 64;

    // [D] issue next-tile staging (K -> regs, V -> LDS via DMA)
    float4 kvec;
    if (tid < 256)
      kvec = *reinterpret_cast<const float4*>(kT + ((size_t)b*4096 + kv0n + kv_s)*16 + 4*t4v);
    {
      const u16* vsrc = vT + (size_t)b*256*4096 + kv0n;
#pragma unroll
      for (int i = 0; i < 4; ++i) {
        int u = i*512 + tid;
        int row = u >> 3, slot = u & 7;
        int sb = (slot*16) ^ ((row & 7) << 4);
        gl2lds16((const char*)(vsrc + (size_t)row*4096) + sb, (char*)&vbuf[nxt][0] + u*16);
      }
    }

    // [A] scores: 4 kv-subtiles x 2 MFMA (split-bf16)
    f32x4 S[4];
#pragma unroll
    for (int s = 0; s < 4; ++s) {
      bf16x8 bh = __builtin_bit_cast(bf16x8, *reinterpret_cast<const us8*>(&kfh[cur][s][lane][0]));
      bf16x8 bl = __builtin_bit_cast(bf16x8, *reinterpret_cast<const us8*>(&kfl[cur][s][lane][0]));
      f32x4 acc = (f32x4){0.f, 0.f, 0.f, 0.f};
      acc = __builtin_amdgcn_mfma_f32_16x16x32_bf16(A1, bh, acc, 0, 0, 0);
      acc = __builtin_amdgcn_mfma_f32_16x16x32_bf16(A2, bl, acc, 0, 0, 0);
      S[s] = acc;
    }

    // [B] mask + deferred-max online softmax (wave-wide M, THR=8)
    float pmax = -1e30f;
#pragma unroll
    for (int s = 0; s < 4; ++s)
#pragma unroll
      for (int r = 0; r < 4; ++r) {
        float v = S[s][r];
        v = (v < mean) ? 0.f : v;
        S[s][r] = v;
        pmax = fmaxf(pmax, v);
      }
    if (!__all(pmax <= M + 8.0f)) {
      float mw = pmax;
#pragma unroll
      for (int off = 1; off < 64; off <<= 1) mw = fmaxf(mw, __shfl_xor(mw, off));
      float Mn = fmaxf(M, mw);
      float sc = __expf(M - Mn);
#pragma unroll
      for (int i = 0; i < 8; ++i) {
        O[i][0] *= sc; O[i][1] *= sc; O[i][2] *= sc; O[i][3] *= sc;
      }
#pragma unroll
      for (int r = 0; r < 4; ++r) Lr[r] *= sc;
      M = Mn;
    }
    u16 pb[4][4];
#pragma unroll
    for (int s = 0; s < 4; ++s)
#pragma unroll
      for (int r = 0; r < 4; ++r) {
        float p = __expf(S[s][r] - M);
        Lr[r] += p;
        pb[s][r] = __builtin_bit_cast(u16, __float2bfloat16(p));
      }

    // [C] write P into per-wave A-frag copy
    {
      const int ib = lane & 7;
      const int t1 = (lane >> 3) & 1;
#pragma unroll
      for (int s = 0; s < 4; ++s) {
        const int c2 = s >> 1;
        const int ldb = 16 * ((2*s + t1) & 3) + 4*g;
#pragma unroll
        for (int r = 0; r < 4; ++r) pfr[w][c2][ldb + r][ib] = pb[s][r];
      }
    }
    asm volatile("s_waitcnt lgkmcnt(0)" ::: "memory");
    __builtin_amdgcn_sched_barrier(0);

    // [G] PV: 2 k-chunks x 8 c-subtiles (this wave's c-half)
#pragma unroll
    for (int c2 = 0; c2 < 2; ++c2) {
      bf16x8 pa = __builtin_bit_cast(bf16x8, *reinterpret_cast<const us8*>(&pfr[w][c2][lane][0]));
#pragma unroll
      for (int ct = 0; ct < 8; ++ct) {
        int row = (wc*8 + ct)*16 + c16;
        int off = (c2*64 + g*16) ^ ((lane & 7) << 4);
        bf16x8 vb = __builtin_bit_cast(bf16x8,
            *reinterpret_cast<const us8*>((const char*)&vbuf[cur][0] + row*128 + off));
        O[ct] = __builtin_amdgcn_mfma_f32_16x16x32_bf16(pa, vb, O[ct], 0, 0, 0);
      }
    }

    // [H] convert + write K frags for next tile
    if (tid < 256) {
      float kf[4] = {kvec.x, kvec.y, kvec.z, kvec.w};
      us4 h4, l4;
#pragma unroll
      for (int di = 0; di < 4; ++di) {
        __hip_bfloat16 h = __float2bfloat16(kf[di]);
        float fh = __bfloat162float(h);
        __hip_bfloat16 lo = __float2bfloat16(kf[di] - fh);
        h4[di] = __builtin_bit_cast(u16, h);
        l4[di] = __builtin_bit_cast(u16, lo);
      }
      *reinterpret_cast<us4*>(&kfh[nxt][ks][kld0][ki0])    = h4;
      *reinterpret_cast<us4*>(&kfh[nxt][ks][kld0+32][ki0]) = h4;
      *reinterpret_cast<us4*>(&kfl[nxt][ks][kld0][ki0])    = l4;
      *reinterpret_cast<us4*>(&kfl[nxt][ks][kld0+32][ki0]) = l4;
    }

    __syncthreads();
  }

  // ---- epilogue: reduce L across the 16 kv-lanes, write O/L to ods [b][c][n] ----
#pragma unroll
  for (int r = 0; r < 4; ++r) {
    float v = Lr[r];
#pragma unroll
    for (int off = 1; off < 16; off <<= 1) v += __shfl_xor(v, off);
    Lr[r] = v;
  }
  float inv[4];
#pragma unroll
  for (int r = 0; r < 4; ++r) inv[r] = 1.0f / Lr[r];
#pragma unroll
  for (int ct = 0; ct < 8; ++ct) {
    int c = (wc*8 + ct)*16 + c16;
    float* dst = ods + ((size_t)b*256 + c) * 4096u + row0 + 16*wq + 4*g;
    float4 o4 = make_float4(O[ct][0]*inv[0], O[ct][1]*inv[1], O[ct][2]*inv[2], O[ct][3]*inv[3]);
    *reinterpret_cast<float4*>(dst) = o4;
  }
}

// ---------------- bilinear 4x upsample + residual, 4 px/thread ----------------
__global__ __launch_bounds__(256) void k_up(const float* __restrict__ ods, const float* __restrict__ x,
                                            float* __restrict__ out) {
  unsigned idx4 = blockIdx.x * 256u + threadIdx.x;   // < 16777216
  int a  = (int)(idx4 & 63u);          // horizontal cell = output j strip [4a,4a+4)
  int i  = (int)((idx4 >> 6) & 255u);  // output row
  size_t bc = idx4 >> 14;              // b*256 + c

  float py = (i + 0.5f) * 0.25f - 0.5f;
  float y0f = floorf(py);
  float wy = py - y0f;
  int y0 = (int)y0f, y1 = y0 + 1;
  y0 = max(y0, 0); y1 = min(y1, 63);

  int xm1 = max(a - 1, 0), xp1 = min(a + 1, 63);

  const float* r0 = ods + bc * 4096u + y0 * 64;
  const float* r1 = ods + bc * 4096u + y1 * 64;
  float wy1 = 1.f - wy;
  float vm1 = wy1 * r0[xm1] + wy * r1[xm1];
  float v0  = wy1 * r0[a]   + wy * r1[a];
  float vp1 = wy1 * r0[xp1] + wy * r1[xp1];

  float4 xv = *reinterpret_cast<const float4*>(x + (size_t)idx4 * 4u);
  float4 o4;
  o4.x = fmaf(0.375f, vm1, 0.625f * v0) + xv.x;
  o4.y = fmaf(0.125f, vm1, 0.875f * v0) + xv.y;
  o4.z = fmaf(0.875f, v0, 0.125f * vp1) + xv.z;
  o4.w = fmaf(0.625f, v0, 0.375f * vp1) + xv.w;
  *reinterpret_cast<float4*>(out + (size_t)idx4 * 4u) = o4;
}

extern "C" void kernel_launch(void* const* d_in, const int* in_sizes, int n_in,
                              void* d_out, int out_size, void* d_ws, size_t ws_size,
                              hipStream_t stream) {
  const float* x  = (const float*)d_in[0];
  const float* Wq = (const float*)d_in[1];
  const float* bq = (const float*)d_in[2];
  const float* Wk = (const float*)d_in[3];
  const float* bk = (const float*)d_in[4];
  const float* Wv = (const float*)d_in[5];
  const float* bv = (const float*)d_in[6];
  float* out = (float*)d_out;

  char* ws = (char*)d_ws;
  float* ods   = (float*)(ws + OFF_ODS);
  float* qT    = (float*)(ws + OFF_QT);
  float* kT    = (float*)(ws + OFF_KT);
  u16*   vT    = (u16*)(ws + OFF_VT);
  float* Spart = (float*)(ws + OFF_SPART);
  float* mnp   = (float*)(ws + OFF_MEAN);

  k_front<<<dim3(256), dim3(512), 0, stream>>>(x, Wq, bq, Wk, bk, Wv, bv, qT, kT, vT, Spart);
  k_mean<<<dim3(1), dim3(64), 0, stream>>>(Spart, bq, bk, mnp);
  k_flash<<<dim3(256), dim3(512), 0, stream>>>(qT, kT, vT, mnp, ods);
  k_up<<<dim3(65536), dim3(256), 0, stream>>>(ods, x, out);
}